// Round 3
// baseline (555.713 us; speedup 1.0000x reference)
//
#include <hip/hip_runtime.h>

#define N_IN 512
#define HID 64
#define NBLK 256   // edge-chunk count for hist/partition passes

typedef __attribute__((ext_vector_type(4))) float f32x4;
typedef __attribute__((ext_vector_type(8))) short bf16x8;

__device__ inline float bf2f(unsigned short s) {
    union { unsigned int u; float f; } v; v.u = ((unsigned int)s) << 16; return v.f;
}
__device__ inline unsigned short f2bf(float f) {
    union { float f; unsigned int u; } v; v.f = f;
    unsigned int u = v.u;
    return (unsigned short)((u + 0x7FFFu + ((u >> 16) & 1u)) >> 16);
}

// ---- pass A: per-(bucket, chunk) histogram (LDS atomics) + W1 transpose ----
__global__ __launch_bounds__(1024) void k_histA_wt(const int* __restrict__ EI, int* __restrict__ hist,
                                                   const float* __restrict__ W1, unsigned short* __restrict__ Wt,
                                                   int E, int N, int K) {
    int tid = threadIdx.x;
    if (blockIdx.x >= NBLK) {   // W1 [512][64] fp32 -> Wt [64][512] bf16
        int i = (blockIdx.x - NBLK) * 1024 + tid;
        if (i < N_IN * HID) {
            int k = i >> 6, n = i & 63;
            Wt[n * 512 + k] = f2bf(W1[i]);
        }
        return;
    }
    __shared__ int hs[512];
    __shared__ int sflag;
    if (tid == 0) sflag = (EI[1] == 0 && EI[3] == 0 && EI[5] == 0 && EI[7] == 0) ? 1 : 0;
    if (tid < 512) hs[tid] = 0;
    __syncthreads();
    bool f = sflag != 0;
    int chunk = (E + NBLK - 1) / NBLK;
    int s = blockIdx.x * chunk, e = min(E, s + chunk);
    for (int i = s + tid; i < e; i += 1024) {
        int c = f ? ((const int2*)EI)[E + i].x : EI[E + i];
        if ((unsigned)c < (unsigned)N) atomicAdd(&hs[c >> 8], 1);
    }
    __syncthreads();
    for (int k = tid; k < K; k += 1024) hist[k * NBLK + blockIdx.x] = hs[k];
}

// ---- block-local exclusive scan over hist (in-place) ----
__global__ __launch_bounds__(256) void k_scan_a2(int* __restrict__ data, int* __restrict__ bsum, int n) {
    __shared__ int sd[256];
    int i = blockIdx.x * 256 + threadIdx.x;
    int v = (i < n) ? data[i] : 0;
    sd[threadIdx.x] = v;
    __syncthreads();
    for (int off = 1; off < 256; off <<= 1) {
        int t = 0;
        if (threadIdx.x >= (unsigned)off) t = sd[threadIdx.x - off];
        __syncthreads();
        sd[threadIdx.x] += t;
        __syncthreads();
    }
    if (i < n) data[i] = sd[threadIdx.x] - v;
    if (threadIdx.x == 255) bsum[blockIdx.x] = sd[255];
}

// also zeroes the pad rows (row N) of h1/h2 used by predicated gathers
__global__ __launch_bounds__(512) void k_scan_b(const int* __restrict__ bsum, int* __restrict__ bexc, int nb,
                                                unsigned short* __restrict__ h1, unsigned short* __restrict__ h2,
                                                int N) {
    __shared__ int sd[512];
    int t = threadIdx.x;
    if (t < 32) ((unsigned int*)(h1 + (size_t)N * 64))[t] = 0;          // 128B zero row
    if (t >= 32 && t < 40) ((unsigned int*)(h2 + (size_t)N * 16))[t - 32] = 0;  // 32B zero row
    int v = (t < nb) ? bsum[t] : 0;
    sd[t] = v;
    __syncthreads();
    for (int off = 1; off < 512; off <<= 1) {
        int u = 0;
        if (t >= off) u = sd[t - off];
        __syncthreads();
        sd[t] += u;
        __syncthreads();
    }
    if (t < nb) bexc[t] = sd[t] - v;
    if (t == 511) bexc[nb] = sd[511];
}

// ---- pass B: simple scatter ------------------------------------------------
__global__ __launch_bounds__(1024) void k_partB(const int* __restrict__ EI, const int* __restrict__ hist,
                                                const int* __restrict__ bexc, int* __restrict__ edges2,
                                                int E, int N, int K) {
    __shared__ int cur[512];
    __shared__ int sflag;
    int tid = threadIdx.x, b = blockIdx.x;
    if (tid == 0) sflag = (EI[1] == 0 && EI[3] == 0 && EI[5] == 0 && EI[7] == 0) ? 1 : 0;
    if (tid < 512) cur[tid] = (tid < K) ? (bexc[tid] + hist[tid * NBLK + b]) : 0;
    __syncthreads();
    bool f = sflag != 0;
    int chunk = (E + NBLK - 1) / NBLK;
    int s = b * chunk, e = min(E, s + chunk);
    for (int i = s + tid; i < e; i += 1024) {
        int r, c;
        if (f) { const int2* E2 = (const int2*)EI; r = E2[i].x; c = E2[E + i].x; }
        else   { r = EI[i]; c = EI[E + i]; }
        if ((unsigned)r >= (unsigned)N || (unsigned)c >= (unsigned)N) continue;
        int pos = atomicAdd(&cur[c >> 8], 1);
        edges2[pos] = r | ((c & 255) << 20);   // r < 2^20, c_local in bits 20..27
    }
}

// ---- GEMM1 (MFMA, no LDS): H[m] = X[m]·W1 bf16 (raw; dinv applied in bucket)
__global__ __launch_bounds__(256) void k_gemm1(const float* __restrict__ X, const unsigned short* __restrict__ Wt,
                                               unsigned short* __restrict__ H, int N) {
    int tid = threadIdx.x;
    int w = tid >> 6, lane = tid & 63;
    int m_l = lane & 15, q = lane >> 4;
    int m0 = blockIdx.x * 128 + w * 32;
    int rA0 = m0 + m_l, rA1 = m0 + 16 + m_l;
    int rc0 = rA0 < N ? rA0 : N - 1;
    int rc1 = rA1 < N ? rA1 : N - 1;
    const float* baseA0 = X + (size_t)rc0 * 512 + q * 8;
    const float* baseA1 = X + (size_t)rc1 * 512 + q * 8;
    const unsigned short* baseB = Wt + (size_t)m_l * 512 + q * 8;

    f32x4 acc[2][4] = {};
#pragma unroll 4
    for (int c = 0; c < 16; ++c) {
        int ko = c * 32;
        float4 x0a = *(const float4*)(baseA0 + ko);
        float4 x0b = *(const float4*)(baseA0 + ko + 4);
        float4 x1a = *(const float4*)(baseA1 + ko);
        float4 x1b = *(const float4*)(baseA1 + ko + 4);
        bf16x8 a0, a1;
        a0[0] = (short)f2bf(x0a.x); a0[1] = (short)f2bf(x0a.y); a0[2] = (short)f2bf(x0a.z); a0[3] = (short)f2bf(x0a.w);
        a0[4] = (short)f2bf(x0b.x); a0[5] = (short)f2bf(x0b.y); a0[6] = (short)f2bf(x0b.z); a0[7] = (short)f2bf(x0b.w);
        a1[0] = (short)f2bf(x1a.x); a1[1] = (short)f2bf(x1a.y); a1[2] = (short)f2bf(x1a.z); a1[3] = (short)f2bf(x1a.w);
        a1[4] = (short)f2bf(x1b.x); a1[5] = (short)f2bf(x1b.y); a1[6] = (short)f2bf(x1b.z); a1[7] = (short)f2bf(x1b.w);
#pragma unroll
        for (int t = 0; t < 4; ++t) {
            bf16x8 bb = *(const bf16x8*)(baseB + (size_t)t * 16 * 512 + ko);
            acc[0][t] = __builtin_amdgcn_mfma_f32_16x16x32_bf16(a0, bb, acc[0][t], 0, 0, 0);
            acc[1][t] = __builtin_amdgcn_mfma_f32_16x16x32_bf16(a1, bb, acc[1][t], 0, 0, 0);
        }
    }
#pragma unroll
    for (int h = 0; h < 2; ++h) {
#pragma unroll
        for (int rg = 0; rg < 4; ++rg) {
            int row = m0 + h * 16 + q * 4 + rg;
            if (row < N) {
#pragma unroll
                for (int t = 0; t < 4; ++t)
                    H[(size_t)row * 64 + t * 16 + m_l] = f2bf(acc[h][t][rg]);
            }
        }
    }
}

// ---- per-bucket: fine CSR (4-aligned starts, start/end/dinv + edge scatter)
// + H prescale. Fine region for bucket b: align4(bexc[b]) + 1024*b, capacity
// = bucket_edges + ~1021 >= sum(deg4) + 127 block over-read. start[] % 4 == 0.
__global__ __launch_bounds__(256) void k_bucket(const int* __restrict__ bexc, const int* __restrict__ edges2,
                                                int* __restrict__ edges, int* __restrict__ start,
                                                int* __restrict__ endv, float* __restrict__ dinv,
                                                unsigned short* __restrict__ H, int N, int K) {
    __shared__ int hist[256], sd[256], cur[256];
    __shared__ float dvs[256];
    int b = blockIdx.x, tid = threadIdx.x;
    int cbase = bexc[b];
    int cend  = bexc[b + 1];
    int base  = ((cbase + 3) & ~3) + 1024 * b;   // 4-aligned fine base
    hist[tid] = 0;
    __syncthreads();
    for (int i = cbase + tid; i < cend; i += 256)
        atomicAdd(&hist[(edges2[i] >> 20) & 255], 1);
    __syncthreads();
    int v = hist[tid];
    int v4 = (v + 3) & ~3;
    sd[tid] = v4;
    __syncthreads();
    for (int off = 1; off < 256; off <<= 1) {
        int t = 0;
        if (tid >= off) t = sd[tid - off];
        __syncthreads();
        sd[tid] += t;
        __syncthreads();
    }
    int excl = sd[tid] - v4;
    cur[tid] = excl;
    int node = b * 256 + tid;
    float dvv = rsqrtf((float)(v + 1));
    dvs[tid] = dvv;
    if (node < N) {
        start[node] = base + excl;
        endv[node]  = base + excl + v;
        dinv[node]  = dvv;
    }
    __syncthreads();
    for (int i = cbase + tid; i < cend; i += 256) {
        int pv = edges2[i];
        int pos = atomicAdd(&cur[(pv >> 20) & 255], 1);
        edges[base + pos] = pv & 0xFFFFF;
    }
    // prescale this bucket's H rows by dinv (16 lanes per row, coalesced)
    for (int rr = tid >> 4; rr < 256; rr += 16) {
        int n2 = b * 256 + rr;
        if (n2 < N) {
            float dv2 = dvs[rr];
            uint2* pp = (uint2*)(H + (size_t)n2 * 64 + (size_t)(tid & 15) * 4);
            uint2 vv = *pp;
            float f0 = bf2f((unsigned short)(vv.x & 0xffffu)) * dv2;
            float f1 = bf2f((unsigned short)(vv.x >> 16)) * dv2;
            float f2 = bf2f((unsigned short)(vv.y & 0xffffu)) * dv2;
            float f3 = bf2f((unsigned short)(vv.y >> 16)) * dv2;
            vv.x = (unsigned int)f2bf(f0) | ((unsigned int)f2bf(f1) << 16);
            vv.y = (unsigned int)f2bf(f2) | ((unsigned int)f2bf(f3) << 16);
            *pp = vv;
        }
    }
}

#define ACC8(v) do { \
    a[0] += __uint_as_float((v).x << 16); \
    a[1] += __uint_as_float((v).x & 0xffff0000u); \
    a[2] += __uint_as_float((v).y << 16); \
    a[3] += __uint_as_float((v).y & 0xffff0000u); \
    a[4] += __uint_as_float((v).z << 16); \
    a[5] += __uint_as_float((v).z & 0xffff0000u); \
    a[6] += __uint_as_float((v).w << 16); \
    a[7] += __uint_as_float((v).w & 0xffff0000u); } while (0)

// ---- fused agg1 + gemm2: wave/node; 8 slots x 8 lanes x uint4 (64 edges/iter,
// 8 gathers of 1KB), predicated to zero-row N, index prefetch one block ahead.
__global__ __launch_bounds__(256) void k_agg1g2(const unsigned short* __restrict__ H, const int* __restrict__ edges,
                                                const int* __restrict__ start, const int* __restrict__ endv,
                                                const float* __restrict__ dinv,
                                                const float* __restrict__ b1, const float* __restrict__ W2,
                                                unsigned short* __restrict__ H2, int N) {
    __shared__ float w2s[64 * 17];   // [k][c] stride 17
    int tid = threadIdx.x;
    for (int i = tid; i < 1024; i += 256) { int k = i >> 4, c = i & 15; w2s[k * 17 + c] = W2[i]; }
    __syncthreads();
    int wid = blockIdx.x * 4 + (tid >> 6);
    int lane = tid & 63;
    if (wid >= N) return;
    int g8 = (lane >> 3) * 8;           // slot-group: edges g8..g8+7 of each block
    int c8 = lane & 7;                  // channels 8*c8 .. 8*c8+7
    const size_t coff = (size_t)c8 * 8;
    float a[8] = {0.f, 0.f, 0.f, 0.f, 0.f, 0.f, 0.f, 0.f};
    int s = start[wid], e = endv[wid];
    int4 s0, s1;
    if (s < e) {                        // start 4-aligned: int4 loads legal
        s0 = *(const int4*)(edges + s + g8);
        s1 = *(const int4*)(edges + s + g8 + 4);
    }
    for (int i = s; i < e; i += 64) {
        int jb = i + g8;
        int i0 = (jb + 0 < e) ? s0.x : N;
        int i1 = (jb + 1 < e) ? s0.y : N;
        int i2 = (jb + 2 < e) ? s0.z : N;
        int i3 = (jb + 3 < e) ? s0.w : N;
        int i4 = (jb + 4 < e) ? s1.x : N;
        int i5 = (jb + 5 < e) ? s1.y : N;
        int i6 = (jb + 6 < e) ? s1.z : N;
        int i7 = (jb + 7 < e) ? s1.w : N;
        uint4 v0 = *(const uint4*)(H + (size_t)i0 * 64 + coff);
        uint4 v1 = *(const uint4*)(H + (size_t)i1 * 64 + coff);
        uint4 v2 = *(const uint4*)(H + (size_t)i2 * 64 + coff);
        uint4 v3 = *(const uint4*)(H + (size_t)i3 * 64 + coff);
        uint4 v4 = *(const uint4*)(H + (size_t)i4 * 64 + coff);
        uint4 v5 = *(const uint4*)(H + (size_t)i5 * 64 + coff);
        uint4 v6 = *(const uint4*)(H + (size_t)i6 * 64 + coff);
        uint4 v7 = *(const uint4*)(H + (size_t)i7 * 64 + coff);
        int ni = i + 64;
        if (ni < e) {                   // prefetch next block's indices
            s0 = *(const int4*)(edges + ni + g8);
            s1 = *(const int4*)(edges + ni + g8 + 4);
        }
        ACC8(v0); ACC8(v1); ACC8(v2); ACC8(v3);
        ACC8(v4); ACC8(v5); ACC8(v6); ACC8(v7);
    }
    // butterfly over the 8 slot-groups: every lane gets full sums for its 8 ch
#pragma unroll
    for (int c = 0; c < 8; ++c) {
        a[c] += __shfl_xor(a[c], 8, 64);
        a[c] += __shfl_xor(a[c], 16, 64);
        a[c] += __shfl_xor(a[c], 32, 64);
    }
    // self term + bias + relu
    float dv = dinv[wid];
    uint4 sv = *(const uint4*)(H + (size_t)wid * 64 + coff);   // prescaled self
    ACC8(sv);
    float4 bva = *(const float4*)(b1 + c8 * 8);
    float4 bvb = *(const float4*)(b1 + c8 * 8 + 4);
    float r[8];
    r[0] = fmaxf(a[0] * dv + bva.x, 0.f);
    r[1] = fmaxf(a[1] * dv + bva.y, 0.f);
    r[2] = fmaxf(a[2] * dv + bva.z, 0.f);
    r[3] = fmaxf(a[3] * dv + bva.w, 0.f);
    r[4] = fmaxf(a[4] * dv + bvb.x, 0.f);
    r[5] = fmaxf(a[5] * dv + bvb.y, 0.f);
    r[6] = fmaxf(a[6] * dv + bvb.z, 0.f);
    r[7] = fmaxf(a[7] * dv + bvb.w, 0.f);
    // fused gemm2: x1[k] lives in lane with c8==k>>3, register k&7.
    // lane (qt=lane>>4, co=lane&15) accumulates k = qt*16 .. qt*16+15.
    int qt = lane >> 4, co = lane & 15;
    float p = 0.f;
#pragma unroll
    for (int j = 0; j < 16; ++j) {
        float xk = __shfl(r[j & 7], qt * 2 + (j >> 3), 64);
        p += xk * w2s[(qt * 16 + j) * 17 + co];
    }
    p += __shfl_xor(p, 16, 64);
    p += __shfl_xor(p, 32, 64);
    if (lane < 16) H2[(size_t)wid * 16 + co] = f2bf(p * dv);
}

// ---- agg2: wave/node, 16 slots x 4 lanes x uint2 (128 edges/iter) ---------
__global__ __launch_bounds__(256) void k_agg2(const unsigned short* __restrict__ H2, const int* __restrict__ edges,
                                              const int* __restrict__ start, const int* __restrict__ endv,
                                              const float* __restrict__ dinv,
                                              const float* __restrict__ b2, float* __restrict__ X2, int N) {
    int wid = blockIdx.x * 4 + (threadIdx.x >> 6);
    int lane = threadIdx.x & 63;
    if (wid >= N) return;
    int g8 = (lane >> 2) * 8;           // 16 slot-groups, 8 edges each
    int c4 = lane & 3;                  // channels 4*c4 .. 4*c4+3
    const size_t coff = (size_t)c4 * 4;
    float a0 = 0.f, a1 = 0.f, a2 = 0.f, a3 = 0.f;
    int s = start[wid], e = endv[wid];
    int4 s0, s1;
    if (s < e) {
        s0 = *(const int4*)(edges + s + g8);
        s1 = *(const int4*)(edges + s + g8 + 4);
    }
    for (int i = s; i < e; i += 128) {
        int jb = i + g8;
        int i0 = (jb + 0 < e) ? s0.x : N;
        int i1 = (jb + 1 < e) ? s0.y : N;
        int i2 = (jb + 2 < e) ? s0.z : N;
        int i3 = (jb + 3 < e) ? s0.w : N;
        int i4 = (jb + 4 < e) ? s1.x : N;
        int i5 = (jb + 5 < e) ? s1.y : N;
        int i6 = (jb + 6 < e) ? s1.z : N;
        int i7 = (jb + 7 < e) ? s1.w : N;
        uint2 v0 = *(const uint2*)(H2 + (size_t)i0 * 16 + coff);
        uint2 v1 = *(const uint2*)(H2 + (size_t)i1 * 16 + coff);
        uint2 v2 = *(const uint2*)(H2 + (size_t)i2 * 16 + coff);
        uint2 v3 = *(const uint2*)(H2 + (size_t)i3 * 16 + coff);
        uint2 v4 = *(const uint2*)(H2 + (size_t)i4 * 16 + coff);
        uint2 v5 = *(const uint2*)(H2 + (size_t)i5 * 16 + coff);
        uint2 v6 = *(const uint2*)(H2 + (size_t)i6 * 16 + coff);
        uint2 v7 = *(const uint2*)(H2 + (size_t)i7 * 16 + coff);
        int ni = i + 128;
        if (ni < e) {
            s0 = *(const int4*)(edges + ni + g8);
            s1 = *(const int4*)(edges + ni + g8 + 4);
        }
        a0 += __uint_as_float(v0.x << 16) + __uint_as_float(v1.x << 16)
            + __uint_as_float(v2.x << 16) + __uint_as_float(v3.x << 16)
            + __uint_as_float(v4.x << 16) + __uint_as_float(v5.x << 16)
            + __uint_as_float(v6.x << 16) + __uint_as_float(v7.x << 16);
        a1 += __uint_as_float(v0.x & 0xffff0000u) + __uint_as_float(v1.x & 0xffff0000u)
            + __uint_as_float(v2.x & 0xffff0000u) + __uint_as_float(v3.x & 0xffff0000u)
            + __uint_as_float(v4.x & 0xffff0000u) + __uint_as_float(v5.x & 0xffff0000u)
            + __uint_as_float(v6.x & 0xffff0000u) + __uint_as_float(v7.x & 0xffff0000u);
        a2 += __uint_as_float(v0.y << 16) + __uint_as_float(v1.y << 16)
            + __uint_as_float(v2.y << 16) + __uint_as_float(v3.y << 16)
            + __uint_as_float(v4.y << 16) + __uint_as_float(v5.y << 16)
            + __uint_as_float(v6.y << 16) + __uint_as_float(v7.y << 16);
        a3 += __uint_as_float(v0.y & 0xffff0000u) + __uint_as_float(v1.y & 0xffff0000u)
            + __uint_as_float(v2.y & 0xffff0000u) + __uint_as_float(v3.y & 0xffff0000u)
            + __uint_as_float(v4.y & 0xffff0000u) + __uint_as_float(v5.y & 0xffff0000u)
            + __uint_as_float(v6.y & 0xffff0000u) + __uint_as_float(v7.y & 0xffff0000u);
    }
    a0 += __shfl_xor(a0, 4, 64); a0 += __shfl_xor(a0, 8, 64); a0 += __shfl_xor(a0, 16, 64); a0 += __shfl_xor(a0, 32, 64);
    a1 += __shfl_xor(a1, 4, 64); a1 += __shfl_xor(a1, 8, 64); a1 += __shfl_xor(a1, 16, 64); a1 += __shfl_xor(a1, 32, 64);
    a2 += __shfl_xor(a2, 4, 64); a2 += __shfl_xor(a2, 8, 64); a2 += __shfl_xor(a2, 16, 64); a2 += __shfl_xor(a2, 32, 64);
    a3 += __shfl_xor(a3, 4, 64); a3 += __shfl_xor(a3, 8, 64); a3 += __shfl_xor(a3, 16, 64); a3 += __shfl_xor(a3, 32, 64);
    if (lane < 4) {
        float dv = dinv[wid];
        uint2 sv = *(const uint2*)(H2 + (size_t)wid * 16 + coff);  // prescaled self
        a0 += __uint_as_float(sv.x << 16);
        a1 += __uint_as_float(sv.x & 0xffff0000u);
        a2 += __uint_as_float(sv.y << 16);
        a3 += __uint_as_float(sv.y & 0xffff0000u);
        float4 bv = *(const float4*)(b2 + c4 * 4);
        float4 o;
        o.x = a0 * dv + bv.x; o.y = a1 * dv + bv.y;
        o.z = a2 * dv + bv.z; o.w = a3 * dv + bv.w;
        *(float4*)(X2 + (size_t)wid * 16 + c4 * 4) = o;
    }
}

// ---- attention head + final linear (LDS-staged coalesced output) ----------
__global__ __launch_bounds__(256) void k_head(const float* __restrict__ X2, const float* __restrict__ G,
                                              const float* __restrict__ AW1, const float* __restrict__ AB1,
                                              const float* __restrict__ AW2, const float* __restrict__ LW,
                                              const float* __restrict__ LB, float* __restrict__ OUT, int N) {
    __shared__ float s_aw1[256], s_ab1[16], s_aw2[16], s_lw[640], s_lb[40];
    __shared__ float s_out[256 * 41];   // stride 41: conflict-light staging
    int tid = threadIdx.x;
    s_aw1[tid] = AW1[tid];
    if (tid < 16) { s_ab1[tid] = AB1[tid]; s_aw2[tid] = AW2[tid]; }
    for (int i = tid; i < 640; i += 256) s_lw[i] = LW[i];
    if (tid < 40) s_lb[tid] = LB[tid];
    __syncthreads();
    int node0 = blockIdx.x * 256;
    int node = node0 + tid;
    if (node < N) {
        float x[16], g[16];
        const float4* xp = (const float4*)(X2 + (size_t)node * 16);
        const float4* gp = (const float4*)(G + (size_t)node * 16);
#pragma unroll
        for (int q = 0; q < 4; ++q) {
            float4 v = xp[q]; x[q*4] = v.x; x[q*4+1] = v.y; x[q*4+2] = v.z; x[q*4+3] = v.w;
            float4 u = gp[q]; g[q*4] = u.x; g[q*4+1] = u.y; g[q*4+2] = u.z; g[q*4+3] = u.w;
        }
        float wx = 0.f, wg = 0.f;
#pragma unroll
        for (int j = 0; j < 16; ++j) {
            float tx = s_ab1[j], tg = s_ab1[j];
#pragma unroll
            for (int c = 0; c < 16; ++c) { tx += x[c] * s_aw1[c*16 + j]; tg += g[c] * s_aw1[c*16 + j]; }
            wx += tanhf(tx) * s_aw2[j];
            wg += tanhf(tg) * s_aw2[j];
        }
        float m = fmaxf(wx, wg);
        float ex = expf(wx - m), eg = expf(wg - m);
        float inv = 1.f / (ex + eg);
        float bx = ex * inv, bg = eg * inv;
        float emb[16];
#pragma unroll
        for (int c = 0; c < 16; ++c) emb[c] = bx * x[c] + bg * g[c];
        for (int o = 0; o < 40; ++o) {
            float a = s_lb[o];
#pragma unroll
            for (int c = 0; c < 16; ++c) a += emb[c] * s_lw[c*40 + o];
            s_out[tid * 41 + o] = a;
        }
    }
    __syncthreads();
    // coalesced write of this block's [256][40] slab
    int lim = min(256, N - node0) * 40;
    for (int i = tid; i < lim; i += 256) {
        int r = i / 40, c = i - r * 40;
        OUT[(size_t)node0 * 40 + i] = s_out[r * 41 + c];
    }
}

extern "C" void kernel_launch(void* const* d_in, const int* in_sizes, int n_in,
                              void* d_out, int out_size, void* d_ws, size_t ws_size,
                              hipStream_t stream) {
    const float* X   = (const float*)d_in[0];
    const int*   EI  = (const int*)d_in[1];
    const float* G   = (const float*)d_in[2];
    const float* W1  = (const float*)d_in[3];
    const float* B1  = (const float*)d_in[4];
    const float* W2  = (const float*)d_in[5];
    const float* B2  = (const float*)d_in[6];
    const float* AW1 = (const float*)d_in[7];
    const float* AB1 = (const float*)d_in[8];
    const float* AW2 = (const float*)d_in[9];
    const float* LW  = (const float*)d_in[10];
    const float* LB  = (const float*)d_in[11];
    float* OUT = (float*)d_out;

    const int N = in_sizes[0] / N_IN;
    const int E = in_sizes[1] / 2;
    const int NB = (N + 255) / 256;
    const int K  = NB;                 // buckets of 256 destination nodes
    const int NH = K * NBLK;           // hist entries
    const int SB = (NH + 255) / 256;   // scan blocks (== K when NBLK == 256)
    const int WB = (N_IN * HID + 1023) / 1024; // wt blocks (1024 thr)
    const int GB = (N + 127) / 128;            // gemm1 blocks

    char* w = (char*)d_ws;
    size_t off = 0;
    auto take = [&](size_t bytes) -> void* {
        void* p = (void*)(w + off);
        off = (off + bytes + 255) & ~(size_t)255;
        return p;
    };
    int*   hist   = (int*)take((size_t)NH * 4);
    int*   bsum   = (int*)take((size_t)SB * 4);
    int*   bexc   = (int*)take((size_t)(SB + 1) * 4);
    int*   startp = (int*)take((size_t)N * 4);
    int*   endp   = (int*)take((size_t)N * 4);
    float* dinvp  = (float*)take((size_t)N * 4);
    int*   edges2 = (int*)take((size_t)E * 4);
    int*   edges  = (int*)take((size_t)(E + 1024 * (size_t)K + 256) * 4); // aligned-CSR slack + over-read pad
    unsigned short* wt = (unsigned short*)take((size_t)N_IN * HID * 2);
    unsigned short* h1 = (unsigned short*)take((size_t)(N + 1) * 64 * 2); // +zero row N
    unsigned short* h2 = (unsigned short*)take((size_t)(N + 1) * 16 * 2); // +zero row N
    float* x2 = (float*)take((size_t)N * 16 * 4);
    (void)ws_size; (void)n_in; (void)out_size;

    k_histA_wt<<<NBLK + WB, 1024, 0, stream>>>(EI, hist, W1, wt, E, N, K);
    k_scan_a2 <<<SB, 256, 0, stream>>>(hist, bsum, NH);
    k_scan_b  <<<1, 512, 0, stream>>>(bsum, bexc, SB, h1, h2, N);
    k_partB   <<<NBLK, 1024, 0, stream>>>(EI, hist, bexc, edges2, E, N, K);
    k_gemm1   <<<GB, 256, 0, stream>>>(X, wt, h1, N);
    k_bucket  <<<K, 256, 0, stream>>>(bexc, edges2, edges, startp, endp, dinvp, h1, N, K);
    k_agg1g2  <<<(N + 3) / 4, 256, 0, stream>>>(h1, edges, startp, endp, dinvp, B1, W2, h2, N);
    k_agg2    <<<(N + 3) / 4, 256, 0, stream>>>(h2, edges, startp, endp, dinvp, B2, x2, N);
    k_head    <<<NB, 256, 0, stream>>>(x2, G, AW1, AB1, AW2, LW, LB, OUT, N);
}

// Round 4
// 547.891 us; speedup vs baseline: 1.0143x; 1.0143x over previous
//
#include <hip/hip_runtime.h>

#define N_IN 512
#define HID 64
#define NBLK 256   // edge-chunk count for hist/partition passes

typedef __attribute__((ext_vector_type(4))) float f32x4;
typedef __attribute__((ext_vector_type(8))) short bf16x8;

__device__ inline float bf2f(unsigned short s) {
    union { unsigned int u; float f; } v; v.u = ((unsigned int)s) << 16; return v.f;
}
__device__ inline unsigned short f2bf(float f) {
    union { float f; unsigned int u; } v; v.f = f;
    unsigned int u = v.u;
    return (unsigned short)((u + 0x7FFFu + ((u >> 16) & 1u)) >> 16);
}

// ---- pass A: per-(bucket, chunk) histogram (LDS atomics) + W1 transpose ----
__global__ __launch_bounds__(1024) void k_histA_wt(const int* __restrict__ EI, int* __restrict__ hist,
                                                   const float* __restrict__ W1, unsigned short* __restrict__ Wt,
                                                   int E, int N, int K) {
    int tid = threadIdx.x;
    if (blockIdx.x >= NBLK) {   // W1 [512][64] fp32 -> Wt [64][512] bf16
        int i = (blockIdx.x - NBLK) * 1024 + tid;
        if (i < N_IN * HID) {
            int k = i >> 6, n = i & 63;
            Wt[n * 512 + k] = f2bf(W1[i]);
        }
        return;
    }
    __shared__ int hs[512];
    __shared__ int sflag;
    if (tid == 0) sflag = (EI[1] == 0 && EI[3] == 0 && EI[5] == 0 && EI[7] == 0) ? 1 : 0;
    if (tid < 512) hs[tid] = 0;
    __syncthreads();
    bool f = sflag != 0;
    int chunk = (E + NBLK - 1) / NBLK;
    int s = blockIdx.x * chunk, e = min(E, s + chunk);
    for (int i = s + tid; i < e; i += 1024) {
        int c = f ? ((const int2*)EI)[E + i].x : EI[E + i];
        if ((unsigned)c < (unsigned)N) atomicAdd(&hs[c >> 8], 1);
    }
    __syncthreads();
    for (int k = tid; k < K; k += 1024) hist[k * NBLK + blockIdx.x] = hs[k];
}

// ---- block-local exclusive scan over hist (in-place) ----
__global__ __launch_bounds__(256) void k_scan_a2(int* __restrict__ data, int* __restrict__ bsum, int n) {
    __shared__ int sd[256];
    int i = blockIdx.x * 256 + threadIdx.x;
    int v = (i < n) ? data[i] : 0;
    sd[threadIdx.x] = v;
    __syncthreads();
    for (int off = 1; off < 256; off <<= 1) {
        int t = 0;
        if (threadIdx.x >= (unsigned)off) t = sd[threadIdx.x - off];
        __syncthreads();
        sd[threadIdx.x] += t;
        __syncthreads();
    }
    if (i < n) data[i] = sd[threadIdx.x] - v;
    if (threadIdx.x == 255) bsum[blockIdx.x] = sd[255];
}

// also zeroes the pad rows (row N) of h1/h2 used by predicated gathers
__global__ __launch_bounds__(512) void k_scan_b(const int* __restrict__ bsum, int* __restrict__ bexc, int nb,
                                                unsigned short* __restrict__ h1, unsigned short* __restrict__ h2,
                                                int N) {
    __shared__ int sd[512];
    int t = threadIdx.x;
    if (t < 32) ((unsigned int*)(h1 + (size_t)N * 64))[t] = 0;          // 128B zero row
    if (t >= 32 && t < 40) ((unsigned int*)(h2 + (size_t)N * 16))[t - 32] = 0;  // 32B zero row
    int v = (t < nb) ? bsum[t] : 0;
    sd[t] = v;
    __syncthreads();
    for (int off = 1; off < 512; off <<= 1) {
        int u = 0;
        if (t >= off) u = sd[t - off];
        __syncthreads();
        sd[t] += u;
        __syncthreads();
    }
    if (t < nb) bexc[t] = sd[t] - v;
    if (t == 511) bexc[nb] = sd[511];
}

// ---- pass B: simple scatter ------------------------------------------------
__global__ __launch_bounds__(1024) void k_partB(const int* __restrict__ EI, const int* __restrict__ hist,
                                                const int* __restrict__ bexc, int* __restrict__ edges2,
                                                int E, int N, int K) {
    __shared__ int cur[512];
    __shared__ int sflag;
    int tid = threadIdx.x, b = blockIdx.x;
    if (tid == 0) sflag = (EI[1] == 0 && EI[3] == 0 && EI[5] == 0 && EI[7] == 0) ? 1 : 0;
    if (tid < 512) cur[tid] = (tid < K) ? (bexc[tid] + hist[tid * NBLK + b]) : 0;
    __syncthreads();
    bool f = sflag != 0;
    int chunk = (E + NBLK - 1) / NBLK;
    int s = b * chunk, e = min(E, s + chunk);
    for (int i = s + tid; i < e; i += 1024) {
        int r, c;
        if (f) { const int2* E2 = (const int2*)EI; r = E2[i].x; c = E2[E + i].x; }
        else   { r = EI[i]; c = EI[E + i]; }
        if ((unsigned)r >= (unsigned)N || (unsigned)c >= (unsigned)N) continue;
        int pos = atomicAdd(&cur[c >> 8], 1);
        edges2[pos] = r | ((c & 255) << 20);   // r < 2^20, c_local in bits 20..27
    }
}

// ---- per-bucket: fine CSR (4-aligned starts, start/end/dinv + edge scatter)
// Fine region for bucket b: align4(bexc[b]) + 1024*b; start[] % 4 == 0.
// (H prescale moved into k_gemm1's epilogue -> bucket must run BEFORE gemm1.)
__global__ __launch_bounds__(256) void k_bucket(const int* __restrict__ bexc, const int* __restrict__ edges2,
                                                int* __restrict__ edges, int* __restrict__ start,
                                                int* __restrict__ endv, float* __restrict__ dinv,
                                                int N, int K) {
    __shared__ int hist[256], sd[256], cur[256];
    int b = blockIdx.x, tid = threadIdx.x;
    int cbase = bexc[b];
    int cend  = bexc[b + 1];
    int base  = ((cbase + 3) & ~3) + 1024 * b;   // 4-aligned fine base
    hist[tid] = 0;
    __syncthreads();
    for (int i = cbase + tid; i < cend; i += 256)
        atomicAdd(&hist[(edges2[i] >> 20) & 255], 1);
    __syncthreads();
    int v = hist[tid];
    int v4 = (v + 3) & ~3;
    sd[tid] = v4;
    __syncthreads();
    for (int off = 1; off < 256; off <<= 1) {
        int t = 0;
        if (tid >= off) t = sd[tid - off];
        __syncthreads();
        sd[tid] += t;
        __syncthreads();
    }
    int excl = sd[tid] - v4;
    cur[tid] = excl;
    int node = b * 256 + tid;
    if (node < N) {
        start[node] = base + excl;
        endv[node]  = base + excl + v;
        dinv[node]  = rsqrtf((float)(v + 1));
    }
    __syncthreads();
    for (int i = cbase + tid; i < cend; i += 256) {
        int pv = edges2[i];
        int pos = atomicAdd(&cur[(pv >> 20) & 255], 1);
        edges[base + pos] = pv & 0xFFFFF;
    }
}

// ---- GEMM1 (MFMA, no LDS): H[m] = dinv[m] * (X[m]·W1) in bf16 -------------
__global__ __launch_bounds__(256) void k_gemm1(const float* __restrict__ X, const unsigned short* __restrict__ Wt,
                                               const float* __restrict__ dinv, unsigned short* __restrict__ H,
                                               int N) {
    int tid = threadIdx.x;
    int w = tid >> 6, lane = tid & 63;
    int m_l = lane & 15, q = lane >> 4;
    int m0 = blockIdx.x * 128 + w * 32;
    int rA0 = m0 + m_l, rA1 = m0 + 16 + m_l;
    int rc0 = rA0 < N ? rA0 : N - 1;
    int rc1 = rA1 < N ? rA1 : N - 1;
    const float* baseA0 = X + (size_t)rc0 * 512 + q * 8;
    const float* baseA1 = X + (size_t)rc1 * 512 + q * 8;
    const unsigned short* baseB = Wt + (size_t)m_l * 512 + q * 8;

    f32x4 acc[2][4] = {};
#pragma unroll 4
    for (int c = 0; c < 16; ++c) {
        int ko = c * 32;
        float4 x0a = *(const float4*)(baseA0 + ko);
        float4 x0b = *(const float4*)(baseA0 + ko + 4);
        float4 x1a = *(const float4*)(baseA1 + ko);
        float4 x1b = *(const float4*)(baseA1 + ko + 4);
        bf16x8 a0, a1;
        a0[0] = (short)f2bf(x0a.x); a0[1] = (short)f2bf(x0a.y); a0[2] = (short)f2bf(x0a.z); a0[3] = (short)f2bf(x0a.w);
        a0[4] = (short)f2bf(x0b.x); a0[5] = (short)f2bf(x0b.y); a0[6] = (short)f2bf(x0b.z); a0[7] = (short)f2bf(x0b.w);
        a1[0] = (short)f2bf(x1a.x); a1[1] = (short)f2bf(x1a.y); a1[2] = (short)f2bf(x1a.z); a1[3] = (short)f2bf(x1a.w);
        a1[4] = (short)f2bf(x1b.x); a1[5] = (short)f2bf(x1b.y); a1[6] = (short)f2bf(x1b.z); a1[7] = (short)f2bf(x1b.w);
#pragma unroll
        for (int t = 0; t < 4; ++t) {
            bf16x8 bb = *(const bf16x8*)(baseB + (size_t)t * 16 * 512 + ko);
            acc[0][t] = __builtin_amdgcn_mfma_f32_16x16x32_bf16(a0, bb, acc[0][t], 0, 0, 0);
            acc[1][t] = __builtin_amdgcn_mfma_f32_16x16x32_bf16(a1, bb, acc[1][t], 0, 0, 0);
        }
    }
#pragma unroll
    for (int h = 0; h < 2; ++h) {
#pragma unroll
        for (int rg = 0; rg < 4; ++rg) {
            int row = m0 + h * 16 + q * 4 + rg;
            if (row < N) {
                float dv = dinv[row];
#pragma unroll
                for (int t = 0; t < 4; ++t)
                    H[(size_t)row * 64 + t * 16 + m_l] = f2bf(acc[h][t][rg] * dv);
            }
        }
    }
}

// ---- fused agg1 + gemm2: wave/node; predicated full-width 32-edge blocks
// with index clamp to zero-row N, index prefetch one block ahead.
__global__ __launch_bounds__(256) void k_agg1g2(const unsigned short* __restrict__ H, const int* __restrict__ edges,
                                                const int* __restrict__ start, const int* __restrict__ endv,
                                                const float* __restrict__ dinv,
                                                const float* __restrict__ b1, const float* __restrict__ W2,
                                                unsigned short* __restrict__ H2, int N) {
    __shared__ float w2s[64 * 17];   // [k][c] stride 17: 2-way bank alias only
    int tid = threadIdx.x;
    for (int i = tid; i < 1024; i += 256) { int k = i >> 4, c = i & 15; w2s[k * 17 + c] = W2[i]; }
    __syncthreads();
    int wid = blockIdx.x * 4 + (tid >> 6);
    int lane = tid & 63;
    if (wid >= N) return;
    int g = lane >> 4;                  // edge slot 0..3
    int c4 = lane & 15;                 // channel group: channels c4*4 .. +3
    const size_t coff = (size_t)c4 * 4;
    float a0 = 0.f, a1 = 0.f, a2 = 0.f, a3 = 0.f;
    int s = start[wid], e = endv[wid];
    int4 s0, s1;
    if (s < e) {                        // start is 4-aligned: int4 loads legal
        s0 = *(const int4*)(edges + s + g * 4);
        s1 = *(const int4*)(edges + s + 16 + g * 4);
    }
    for (int i = s; i < e; i += 32) {
        int jb0 = i + g * 4, jb1 = i + 16 + g * 4;
        int i0 = (jb0 + 0 < e) ? s0.x : N;
        int i1 = (jb0 + 1 < e) ? s0.y : N;
        int i2 = (jb0 + 2 < e) ? s0.z : N;
        int i3 = (jb0 + 3 < e) ? s0.w : N;
        int i4 = (jb1 + 0 < e) ? s1.x : N;
        int i5 = (jb1 + 1 < e) ? s1.y : N;
        int i6 = (jb1 + 2 < e) ? s1.z : N;
        int i7 = (jb1 + 3 < e) ? s1.w : N;
        uint2 v0 = *(const uint2*)(H + (size_t)i0 * 64 + coff);
        uint2 v1 = *(const uint2*)(H + (size_t)i1 * 64 + coff);
        uint2 v2 = *(const uint2*)(H + (size_t)i2 * 64 + coff);
        uint2 v3 = *(const uint2*)(H + (size_t)i3 * 64 + coff);
        uint2 v4 = *(const uint2*)(H + (size_t)i4 * 64 + coff);
        uint2 v5 = *(const uint2*)(H + (size_t)i5 * 64 + coff);
        uint2 v6 = *(const uint2*)(H + (size_t)i6 * 64 + coff);
        uint2 v7 = *(const uint2*)(H + (size_t)i7 * 64 + coff);
        int ni = i + 32;
        if (ni < e) {                   // prefetch next block's indices
            s0 = *(const int4*)(edges + ni + g * 4);
            s1 = *(const int4*)(edges + ni + 16 + g * 4);
        }
        a0 += __uint_as_float(v0.x << 16) + __uint_as_float(v1.x << 16)
            + __uint_as_float(v2.x << 16) + __uint_as_float(v3.x << 16)
            + __uint_as_float(v4.x << 16) + __uint_as_float(v5.x << 16)
            + __uint_as_float(v6.x << 16) + __uint_as_float(v7.x << 16);
        a1 += __uint_as_float(v0.x & 0xffff0000u) + __uint_as_float(v1.x & 0xffff0000u)
            + __uint_as_float(v2.x & 0xffff0000u) + __uint_as_float(v3.x & 0xffff0000u)
            + __uint_as_float(v4.x & 0xffff0000u) + __uint_as_float(v5.x & 0xffff0000u)
            + __uint_as_float(v6.x & 0xffff0000u) + __uint_as_float(v7.x & 0xffff0000u);
        a2 += __uint_as_float(v0.y << 16) + __uint_as_float(v1.y << 16)
            + __uint_as_float(v2.y << 16) + __uint_as_float(v3.y << 16)
            + __uint_as_float(v4.y << 16) + __uint_as_float(v5.y << 16)
            + __uint_as_float(v6.y << 16) + __uint_as_float(v7.y << 16);
        a3 += __uint_as_float(v0.y & 0xffff0000u) + __uint_as_float(v1.y & 0xffff0000u)
            + __uint_as_float(v2.y & 0xffff0000u) + __uint_as_float(v3.y & 0xffff0000u)
            + __uint_as_float(v4.y & 0xffff0000u) + __uint_as_float(v5.y & 0xffff0000u)
            + __uint_as_float(v6.y & 0xffff0000u) + __uint_as_float(v7.y & 0xffff0000u);
    }
    // butterfly: every lane gets the full edge-sum for its channel group
    a0 += __shfl_xor(a0, 16, 64); a0 += __shfl_xor(a0, 32, 64);
    a1 += __shfl_xor(a1, 16, 64); a1 += __shfl_xor(a1, 32, 64);
    a2 += __shfl_xor(a2, 16, 64); a2 += __shfl_xor(a2, 32, 64);
    a3 += __shfl_xor(a3, 16, 64); a3 += __shfl_xor(a3, 32, 64);
    // self term + bias + relu (uniform across the 4 slot-groups)
    float dv = dinv[wid];
    uint2 sv = *(const uint2*)(H + (size_t)wid * 64 + coff);   // prescaled self
    a0 += __uint_as_float(sv.x << 16);
    a1 += __uint_as_float(sv.x & 0xffff0000u);
    a2 += __uint_as_float(sv.y << 16);
    a3 += __uint_as_float(sv.y & 0xffff0000u);
    float4 bv = *(const float4*)(b1 + c4 * 4);
    float r0 = fmaxf(a0 * dv + bv.x, 0.f);
    float r1 = fmaxf(a1 * dv + bv.y, 0.f);
    float r2 = fmaxf(a2 * dv + bv.z, 0.f);
    float r3 = fmaxf(a3 * dv + bv.w, 0.f);
    // fused gemm2: out[c4] = dv * sum_k x1[k]*W2[k][c4]; lane's k-quarter = g
    float p = 0.f;
#pragma unroll
    for (int j = 0; j < 4; ++j) {
        int src = 4 * g + j;
        float x0 = __shfl(r0, src, 64);
        float x1 = __shfl(r1, src, 64);
        float x2 = __shfl(r2, src, 64);
        float x3 = __shfl(r3, src, 64);
        int kb = 16 * g + 4 * j;
        p += x0 * w2s[(kb + 0) * 17 + c4];
        p += x1 * w2s[(kb + 1) * 17 + c4];
        p += x2 * w2s[(kb + 2) * 17 + c4];
        p += x3 * w2s[(kb + 3) * 17 + c4];
    }
    p += __shfl_xor(p, 16, 64);
    p += __shfl_xor(p, 32, 64);
    if (g == 0) H2[(size_t)wid * 16 + c4] = f2bf(p * dv);
}

// ---- agg2 + attention head + final linear, fused: wave/node ---------------
// Gather phase identical to R2's k_agg2 (8 slots x 8 lanes x uint, 64/iter).
// Epilogue: broadcast x-row to all lanes, j-parallel tanh attention,
// softmax over {x, glob}, emb, 40-wide output linear.
__global__ __launch_bounds__(256) void k_agg2h(const unsigned short* __restrict__ H2, const int* __restrict__ edges,
                                               const int* __restrict__ start, const int* __restrict__ endv,
                                               const float* __restrict__ dinv, const float* __restrict__ b2,
                                               const float* __restrict__ G,
                                               const float* __restrict__ AW1, const float* __restrict__ AB1,
                                               const float* __restrict__ AW2, const float* __restrict__ LW,
                                               const float* __restrict__ LB, float* __restrict__ OUT, int N) {
    __shared__ float s_aw1[256], s_ab1[16], s_aw2[16], s_lw[640], s_lb[40];
    int tid = threadIdx.x;
    s_aw1[tid] = AW1[tid];
    if (tid < 16) { s_ab1[tid] = AB1[tid]; s_aw2[tid] = AW2[tid]; }
    for (int i = tid; i < 640; i += 256) s_lw[i] = LW[i];
    if (tid < 40) s_lb[tid] = LB[tid];
    __syncthreads();
    int wid = blockIdx.x * 4 + (tid >> 6);
    int lane = tid & 63;
    if (wid >= N) return;
    int g = lane >> 3;                  // edge slot 0..7
    int c2 = lane & 7;                  // channels 2*c2, 2*c2+1
    const size_t coff = (size_t)c2 * 2;
    float a0 = 0.f, a1 = 0.f;
    int s = start[wid], e = endv[wid];
    int4 s0, s1;
    if (s < e) {
        s0 = *(const int4*)(edges + s + g * 4);
        s1 = *(const int4*)(edges + s + 32 + g * 4);
    }
    for (int i = s; i < e; i += 64) {
        int jb0 = i + g * 4, jb1 = i + 32 + g * 4;
        int i0 = (jb0 + 0 < e) ? s0.x : N;
        int i1 = (jb0 + 1 < e) ? s0.y : N;
        int i2 = (jb0 + 2 < e) ? s0.z : N;
        int i3 = (jb0 + 3 < e) ? s0.w : N;
        int i4 = (jb1 + 0 < e) ? s1.x : N;
        int i5 = (jb1 + 1 < e) ? s1.y : N;
        int i6 = (jb1 + 2 < e) ? s1.z : N;
        int i7 = (jb1 + 3 < e) ? s1.w : N;
        unsigned int v0 = *(const unsigned int*)(H2 + (size_t)i0 * 16 + coff);
        unsigned int v1 = *(const unsigned int*)(H2 + (size_t)i1 * 16 + coff);
        unsigned int v2 = *(const unsigned int*)(H2 + (size_t)i2 * 16 + coff);
        unsigned int v3 = *(const unsigned int*)(H2 + (size_t)i3 * 16 + coff);
        unsigned int v4 = *(const unsigned int*)(H2 + (size_t)i4 * 16 + coff);
        unsigned int v5 = *(const unsigned int*)(H2 + (size_t)i5 * 16 + coff);
        unsigned int v6 = *(const unsigned int*)(H2 + (size_t)i6 * 16 + coff);
        unsigned int v7 = *(const unsigned int*)(H2 + (size_t)i7 * 16 + coff);
        int ni = i + 64;
        if (ni < e) {
            s0 = *(const int4*)(edges + ni + g * 4);
            s1 = *(const int4*)(edges + ni + 32 + g * 4);
        }
        a0 += __uint_as_float(v0 << 16) + __uint_as_float(v1 << 16)
            + __uint_as_float(v2 << 16) + __uint_as_float(v3 << 16)
            + __uint_as_float(v4 << 16) + __uint_as_float(v5 << 16)
            + __uint_as_float(v6 << 16) + __uint_as_float(v7 << 16);
        a1 += __uint_as_float(v0 & 0xffff0000u) + __uint_as_float(v1 & 0xffff0000u)
            + __uint_as_float(v2 & 0xffff0000u) + __uint_as_float(v3 & 0xffff0000u)
            + __uint_as_float(v4 & 0xffff0000u) + __uint_as_float(v5 & 0xffff0000u)
            + __uint_as_float(v6 & 0xffff0000u) + __uint_as_float(v7 & 0xffff0000u);
    }
    a0 += __shfl_xor(a0, 8, 64); a0 += __shfl_xor(a0, 16, 64); a0 += __shfl_xor(a0, 32, 64);
    a1 += __shfl_xor(a1, 8, 64); a1 += __shfl_xor(a1, 16, 64); a1 += __shfl_xor(a1, 32, 64);
    // a0/a1 now uniform within each lane&7 class: lane l holds channels
    // 2*(l&7), 2*(l&7)+1. Finish GCN layer 2 on all lanes (redundant, cheap).
    float dv = dinv[wid];
    unsigned int sv = *(const unsigned int*)(H2 + (size_t)wid * 16 + coff);  // prescaled self
    a0 += __uint_as_float(sv << 16);
    a1 += __uint_as_float(sv & 0xffff0000u);
    float2 bv = *(const float2*)(b2 + c2 * 2);
    a0 = a0 * dv + bv.x;
    a1 = a1 * dv + bv.y;
    // broadcast full x-row to every lane
    float x[16];
#pragma unroll
    for (int c = 0; c < 16; ++c) x[c] = __shfl((c & 1) ? a1 : a0, c >> 1, 64);
    // glob row (uniform address -> broadcast load)
    float gl[16];
    const float4* gp = (const float4*)(G + (size_t)wid * 16);
#pragma unroll
    for (int q = 0; q < 4; ++q) {
        float4 u = gp[q];
        gl[q * 4] = u.x; gl[q * 4 + 1] = u.y; gl[q * 4 + 2] = u.z; gl[q * 4 + 3] = u.w;
    }
    // attention logits: 16-lane groups; groups 0,2 -> x, groups 1,3 -> glob
    int j = lane & 15;
    bool isg = (lane >> 4) & 1;
    float t = s_ab1[j];
#pragma unroll
    for (int c = 0; c < 16; ++c) t += (isg ? gl[c] : x[c]) * s_aw1[c * 16 + j];
    float u = tanhf(t) * s_aw2[j];
    u += __shfl_xor(u, 1, 64); u += __shfl_xor(u, 2, 64);
    u += __shfl_xor(u, 4, 64); u += __shfl_xor(u, 8, 64);
    float wx = __shfl(u, 0, 64);
    float wg = __shfl(u, 16, 64);
    float m = fmaxf(wx, wg);
    float ex = expf(wx - m), eg = expf(wg - m);
    float inv = 1.f / (ex + eg);
    float bx = ex * inv, bg = eg * inv;
    // output linear: lane o < 40 computes one output column
    if (lane < 40) {
        float acc = s_lb[lane];
#pragma unroll
        for (int c = 0; c < 16; ++c) acc += (bx * x[c] + bg * gl[c]) * s_lw[c * 40 + lane];
        OUT[(size_t)wid * 40 + lane] = acc;
    }
}

extern "C" void kernel_launch(void* const* d_in, const int* in_sizes, int n_in,
                              void* d_out, int out_size, void* d_ws, size_t ws_size,
                              hipStream_t stream) {
    const float* X   = (const float*)d_in[0];
    const int*   EI  = (const int*)d_in[1];
    const float* G   = (const float*)d_in[2];
    const float* W1  = (const float*)d_in[3];
    const float* B1  = (const float*)d_in[4];
    const float* W2  = (const float*)d_in[5];
    const float* B2  = (const float*)d_in[6];
    const float* AW1 = (const float*)d_in[7];
    const float* AB1 = (const float*)d_in[8];
    const float* AW2 = (const float*)d_in[9];
    const float* LW  = (const float*)d_in[10];
    const float* LB  = (const float*)d_in[11];
    float* OUT = (float*)d_out;

    const int N = in_sizes[0] / N_IN;
    const int E = in_sizes[1] / 2;
    const int NB = (N + 255) / 256;
    const int K  = NB;                 // buckets of 256 destination nodes
    const int NH = K * NBLK;           // hist entries
    const int SB = (NH + 255) / 256;   // scan blocks (== K when NBLK == 256)
    const int WB = (N_IN * HID + 1023) / 1024; // wt blocks (1024 thr)
    const int GB = (N + 127) / 128;            // gemm1 blocks

    char* w = (char*)d_ws;
    size_t off = 0;
    auto take = [&](size_t bytes) -> void* {
        void* p = (void*)(w + off);
        off = (off + bytes + 255) & ~(size_t)255;
        return p;
    };
    int*   hist   = (int*)take((size_t)NH * 4);
    int*   bsum   = (int*)take((size_t)SB * 4);
    int*   bexc   = (int*)take((size_t)(SB + 1) * 4);
    int*   startp = (int*)take((size_t)N * 4);
    int*   endp   = (int*)take((size_t)N * 4);
    float* dinvp  = (float*)take((size_t)N * 4);
    int*   edges2 = (int*)take((size_t)E * 4);
    int*   edges  = (int*)take((size_t)(E + 1024 * (size_t)K + 256) * 4); // aligned-CSR slack + over-read pad
    unsigned short* wt = (unsigned short*)take((size_t)N_IN * HID * 2);
    unsigned short* h1 = (unsigned short*)take((size_t)(N + 1) * 64 * 2); // +zero row N
    unsigned short* h2 = (unsigned short*)take((size_t)(N + 1) * 16 * 2); // +zero row N
    (void)ws_size; (void)n_in; (void)out_size;

    k_histA_wt<<<NBLK + WB, 1024, 0, stream>>>(EI, hist, W1, wt, E, N, K);
    k_scan_a2 <<<SB, 256, 0, stream>>>(hist, bsum, NH);
    k_scan_b  <<<1, 512, 0, stream>>>(bsum, bexc, SB, h1, h2, N);
    k_partB   <<<NBLK, 1024, 0, stream>>>(EI, hist, bexc, edges2, E, N, K);
    k_bucket  <<<K, 256, 0, stream>>>(bexc, edges2, edges, startp, endp, dinvp, N, K);
    k_gemm1   <<<GB, 256, 0, stream>>>(X, wt, dinvp, h1, N);
    k_agg1g2  <<<(N + 3) / 4, 256, 0, stream>>>(h1, edges, startp, endp, dinvp, B1, W2, h2, N);
    k_agg2h   <<<(N + 3) / 4, 256, 0, stream>>>(h2, edges, startp, endp, dinvp, B2, G,
                                                AW1, AB1, AW2, LW, LB, OUT, N);
}

// Round 5
// 527.118 us; speedup vs baseline: 1.0542x; 1.0394x over previous
//
#include <hip/hip_runtime.h>

#define N_IN 512
#define HID 64
#define NBLK 256   // edge-chunk count for hist/partition passes

typedef __attribute__((ext_vector_type(4))) float f32x4;
typedef __attribute__((ext_vector_type(8))) short bf16x8;

__device__ inline float bf2f(unsigned short s) {
    union { unsigned int u; float f; } v; v.u = ((unsigned int)s) << 16; return v.f;
}
__device__ inline unsigned short f2bf(float f) {
    union { float f; unsigned int u; } v; v.f = f;
    unsigned int u = v.u;
    return (unsigned short)((u + 0x7FFFu + ((u >> 16) & 1u)) >> 16);
}

// ---- pass A: per-(bucket, chunk) histogram (LDS atomics) + W1 transpose ----
__global__ __launch_bounds__(1024) void k_histA_wt(const int* __restrict__ EI, int* __restrict__ hist,
                                                   const float* __restrict__ W1, unsigned short* __restrict__ Wt,
                                                   int E, int N, int K) {
    int tid = threadIdx.x;
    if (blockIdx.x >= NBLK) {   // W1 [512][64] fp32 -> Wt [64][512] bf16
        int i = (blockIdx.x - NBLK) * 1024 + tid;
        if (i < N_IN * HID) {
            int k = i >> 6, n = i & 63;
            Wt[n * 512 + k] = f2bf(W1[i]);
        }
        return;
    }
    __shared__ int hs[512];
    __shared__ int sflag;
    if (tid == 0) sflag = (EI[1] == 0 && EI[3] == 0 && EI[5] == 0 && EI[7] == 0) ? 1 : 0;
    if (tid < 512) hs[tid] = 0;
    __syncthreads();
    bool f = sflag != 0;
    int chunk = (E + NBLK - 1) / NBLK;
    int s = blockIdx.x * chunk, e = min(E, s + chunk);
    for (int i = s + tid; i < e; i += 1024) {
        int c = f ? ((const int2*)EI)[E + i].x : EI[E + i];
        if ((unsigned)c < (unsigned)N) atomicAdd(&hs[c >> 8], 1);
    }
    __syncthreads();
    for (int k = tid; k < K; k += 1024) hist[k * NBLK + blockIdx.x] = hs[k];
}

// ---- block-local exclusive scan over hist (in-place) ----
__global__ __launch_bounds__(256) void k_scan_a2(int* __restrict__ data, int* __restrict__ bsum, int n) {
    __shared__ int sd[256];
    int i = blockIdx.x * 256 + threadIdx.x;
    int v = (i < n) ? data[i] : 0;
    sd[threadIdx.x] = v;
    __syncthreads();
    for (int off = 1; off < 256; off <<= 1) {
        int t = 0;
        if (threadIdx.x >= (unsigned)off) t = sd[threadIdx.x - off];
        __syncthreads();
        sd[threadIdx.x] += t;
        __syncthreads();
    }
    if (i < n) data[i] = sd[threadIdx.x] - v;
    if (threadIdx.x == 255) bsum[blockIdx.x] = sd[255];
}

// also zeroes the pad rows (row N) of h1/h2 used by predicated gathers
__global__ __launch_bounds__(512) void k_scan_b(const int* __restrict__ bsum, int* __restrict__ bexc, int nb,
                                                unsigned short* __restrict__ h1, unsigned short* __restrict__ h2,
                                                int N) {
    __shared__ int sd[512];
    int t = threadIdx.x;
    if (t < 32) ((unsigned int*)(h1 + (size_t)N * 64))[t] = 0;          // 128B zero row
    if (t >= 32 && t < 40) ((unsigned int*)(h2 + (size_t)N * 16))[t - 32] = 0;  // 32B zero row
    int v = (t < nb) ? bsum[t] : 0;
    sd[t] = v;
    __syncthreads();
    for (int off = 1; off < 512; off <<= 1) {
        int u = 0;
        if (t >= off) u = sd[t - off];
        __syncthreads();
        sd[t] += u;
        __syncthreads();
    }
    if (t < nb) bexc[t] = sd[t] - v;
    if (t == 511) bexc[nb] = sd[511];
}

// ---- pass B: simple scatter ------------------------------------------------
__global__ __launch_bounds__(1024) void k_partB(const int* __restrict__ EI, const int* __restrict__ hist,
                                                const int* __restrict__ bexc, int* __restrict__ edges2,
                                                int E, int N, int K) {
    __shared__ int cur[512];
    __shared__ int sflag;
    int tid = threadIdx.x, b = blockIdx.x;
    if (tid == 0) sflag = (EI[1] == 0 && EI[3] == 0 && EI[5] == 0 && EI[7] == 0) ? 1 : 0;
    if (tid < 512) cur[tid] = (tid < K) ? (bexc[tid] + hist[tid * NBLK + b]) : 0;
    __syncthreads();
    bool f = sflag != 0;
    int chunk = (E + NBLK - 1) / NBLK;
    int s = b * chunk, e = min(E, s + chunk);
    for (int i = s + tid; i < e; i += 1024) {
        int r, c;
        if (f) { const int2* E2 = (const int2*)EI; r = E2[i].x; c = E2[E + i].x; }
        else   { r = EI[i]; c = EI[E + i]; }
        if ((unsigned)r >= (unsigned)N || (unsigned)c >= (unsigned)N) continue;
        int pos = atomicAdd(&cur[c >> 8], 1);
        edges2[pos] = r | ((c & 255) << 20);   // r < 2^20, c_local in bits 20..27
    }
}

// ---- per-bucket: fine CSR (4-aligned starts, start/end/dinv + edge scatter)
// Fine region for bucket b: align4(bexc[b]) + 1024*b; start[] % 4 == 0.
__global__ __launch_bounds__(256) void k_bucket(const int* __restrict__ bexc, const int* __restrict__ edges2,
                                                int* __restrict__ edges, int* __restrict__ start,
                                                int* __restrict__ endv, float* __restrict__ dinv,
                                                int N, int K) {
    __shared__ int hist[256], sd[256], cur[256];
    int b = blockIdx.x, tid = threadIdx.x;
    int cbase = bexc[b];
    int cend  = bexc[b + 1];
    int base  = ((cbase + 3) & ~3) + 1024 * b;   // 4-aligned fine base
    hist[tid] = 0;
    __syncthreads();
    for (int i = cbase + tid; i < cend; i += 256)
        atomicAdd(&hist[(edges2[i] >> 20) & 255], 1);
    __syncthreads();
    int v = hist[tid];
    int v4 = (v + 3) & ~3;
    sd[tid] = v4;
    __syncthreads();
    for (int off = 1; off < 256; off <<= 1) {
        int t = 0;
        if (tid >= off) t = sd[tid - off];
        __syncthreads();
        sd[tid] += t;
        __syncthreads();
    }
    int excl = sd[tid] - v4;
    cur[tid] = excl;
    int node = b * 256 + tid;
    if (node < N) {
        start[node] = base + excl;
        endv[node]  = base + excl + v;
        dinv[node]  = rsqrtf((float)(v + 1));
    }
    __syncthreads();
    for (int i = cbase + tid; i < cend; i += 256) {
        int pv = edges2[i];
        int pos = atomicAdd(&cur[(pv >> 20) & 255], 1);
        edges[base + pos] = pv & 0xFFFFF;
    }
}

// ---- GEMM1 (MFMA, no LDS): H[m] = dinv[m] * (X[m]·W1) in bf16 -------------
__global__ __launch_bounds__(256) void k_gemm1(const float* __restrict__ X, const unsigned short* __restrict__ Wt,
                                               const float* __restrict__ dinv, unsigned short* __restrict__ H,
                                               int N) {
    int tid = threadIdx.x;
    int w = tid >> 6, lane = tid & 63;
    int m_l = lane & 15, q = lane >> 4;
    int m0 = blockIdx.x * 128 + w * 32;
    int rA0 = m0 + m_l, rA1 = m0 + 16 + m_l;
    int rc0 = rA0 < N ? rA0 : N - 1;
    int rc1 = rA1 < N ? rA1 : N - 1;
    const float* baseA0 = X + (size_t)rc0 * 512 + q * 8;
    const float* baseA1 = X + (size_t)rc1 * 512 + q * 8;
    const unsigned short* baseB = Wt + (size_t)m_l * 512 + q * 8;

    f32x4 acc[2][4] = {};
#pragma unroll 4
    for (int c = 0; c < 16; ++c) {
        int ko = c * 32;
        float4 x0a = *(const float4*)(baseA0 + ko);
        float4 x0b = *(const float4*)(baseA0 + ko + 4);
        float4 x1a = *(const float4*)(baseA1 + ko);
        float4 x1b = *(const float4*)(baseA1 + ko + 4);
        bf16x8 a0, a1;
        a0[0] = (short)f2bf(x0a.x); a0[1] = (short)f2bf(x0a.y); a0[2] = (short)f2bf(x0a.z); a0[3] = (short)f2bf(x0a.w);
        a0[4] = (short)f2bf(x0b.x); a0[5] = (short)f2bf(x0b.y); a0[6] = (short)f2bf(x0b.z); a0[7] = (short)f2bf(x0b.w);
        a1[0] = (short)f2bf(x1a.x); a1[1] = (short)f2bf(x1a.y); a1[2] = (short)f2bf(x1a.z); a1[3] = (short)f2bf(x1a.w);
        a1[4] = (short)f2bf(x1b.x); a1[5] = (short)f2bf(x1b.y); a1[6] = (short)f2bf(x1b.z); a1[7] = (short)f2bf(x1b.w);
#pragma unroll
        for (int t = 0; t < 4; ++t) {
            bf16x8 bb = *(const bf16x8*)(baseB + (size_t)t * 16 * 512 + ko);
            acc[0][t] = __builtin_amdgcn_mfma_f32_16x16x32_bf16(a0, bb, acc[0][t], 0, 0, 0);
            acc[1][t] = __builtin_amdgcn_mfma_f32_16x16x32_bf16(a1, bb, acc[1][t], 0, 0, 0);
        }
    }
#pragma unroll
    for (int h = 0; h < 2; ++h) {
#pragma unroll
        for (int rg = 0; rg < 4; ++rg) {
            int row = m0 + h * 16 + q * 4 + rg;
            if (row < N) {
                float dv = dinv[row];
#pragma unroll
                for (int t = 0; t < 4; ++t)
                    H[(size_t)row * 64 + t * 16 + m_l] = f2bf(acc[h][t][rg] * dv);
            }
        }
    }
}

#define ACC8(v) do { \
    a[0] += __uint_as_float((v).x << 16); \
    a[1] += __uint_as_float((v).x & 0xffff0000u); \
    a[2] += __uint_as_float((v).y << 16); \
    a[3] += __uint_as_float((v).y & 0xffff0000u); \
    a[4] += __uint_as_float((v).z << 16); \
    a[5] += __uint_as_float((v).z & 0xffff0000u); \
    a[6] += __uint_as_float((v).w << 16); \
    a[7] += __uint_as_float((v).w & 0xffff0000u); } while (0)

// ---- fused agg1 + gemm2: wave/node; 8 slot-groups x 8 ch-lanes x uint4.
// 32-edge blocks (matched to deg~32): per iter 1 idx int4 + 4 x 16B gathers.
__global__ __launch_bounds__(256) void k_agg1g2(const unsigned short* __restrict__ H, const int* __restrict__ edges,
                                                const int* __restrict__ start, const int* __restrict__ endv,
                                                const float* __restrict__ dinv,
                                                const float* __restrict__ b1, const float* __restrict__ W2,
                                                unsigned short* __restrict__ H2, int N) {
    __shared__ float w2s[64 * 17];   // [k][c] stride 17
    int tid = threadIdx.x;
    for (int i = tid; i < 1024; i += 256) { int k = i >> 4, c = i & 15; w2s[k * 17 + c] = W2[i]; }
    __syncthreads();
    int wid = blockIdx.x * 4 + (tid >> 6);
    int lane = tid & 63;
    if (wid >= N) return;
    int sg4 = (lane >> 3) * 4;          // slot-group: edges sg4..sg4+3 of each block
    int c8 = lane & 7;                  // channels 8*c8 .. 8*c8+7 (16B of the row)
    const size_t coff = (size_t)c8 * 8;
    float a[8] = {0.f, 0.f, 0.f, 0.f, 0.f, 0.f, 0.f, 0.f};
    int s = start[wid], e = endv[wid];
    int4 s0;
    if (s < e) s0 = *(const int4*)(edges + s + sg4);   // start 4-aligned
    for (int i = s; i < e; i += 32) {
        int jb = i + sg4;
        int i0 = (jb + 0 < e) ? s0.x : N;
        int i1 = (jb + 1 < e) ? s0.y : N;
        int i2 = (jb + 2 < e) ? s0.z : N;
        int i3 = (jb + 3 < e) ? s0.w : N;
        uint4 v0 = *(const uint4*)(H + (size_t)i0 * 64 + coff);
        uint4 v1 = *(const uint4*)(H + (size_t)i1 * 64 + coff);
        uint4 v2 = *(const uint4*)(H + (size_t)i2 * 64 + coff);
        uint4 v3 = *(const uint4*)(H + (size_t)i3 * 64 + coff);
        int ni = i + 32;
        if (ni < e) s0 = *(const int4*)(edges + ni + sg4);   // prefetch
        ACC8(v0); ACC8(v1); ACC8(v2); ACC8(v3);
    }
    // butterfly over the 8 slot-groups
#pragma unroll
    for (int c = 0; c < 8; ++c) {
        a[c] += __shfl_xor(a[c], 8, 64);
        a[c] += __shfl_xor(a[c], 16, 64);
        a[c] += __shfl_xor(a[c], 32, 64);
    }
    // self term + bias + relu
    float dv = dinv[wid];
    uint4 sv = *(const uint4*)(H + (size_t)wid * 64 + coff);   // prescaled self
    ACC8(sv);
    float4 bva = *(const float4*)(b1 + c8 * 8);
    float4 bvb = *(const float4*)(b1 + c8 * 8 + 4);
    float r[8];
    r[0] = fmaxf(a[0] * dv + bva.x, 0.f);
    r[1] = fmaxf(a[1] * dv + bva.y, 0.f);
    r[2] = fmaxf(a[2] * dv + bva.z, 0.f);
    r[3] = fmaxf(a[3] * dv + bva.w, 0.f);
    r[4] = fmaxf(a[4] * dv + bvb.x, 0.f);
    r[5] = fmaxf(a[5] * dv + bvb.y, 0.f);
    r[6] = fmaxf(a[6] * dv + bvb.z, 0.f);
    r[7] = fmaxf(a[7] * dv + bvb.w, 0.f);
    // fused gemm2: x1[k] lives in lane with lane&7==k>>3, register k&7.
    // lane (qt=lane>>4, co=lane&15) accumulates k = qt*16 .. qt*16+15.
    int qt = lane >> 4, co = lane & 15;
    float p = 0.f;
#pragma unroll
    for (int j = 0; j < 16; ++j) {
        float xk = __shfl(r[j & 7], qt * 2 + (j >> 3), 64);
        p += xk * w2s[(qt * 16 + j) * 17 + co];
    }
    p += __shfl_xor(p, 16, 64);
    p += __shfl_xor(p, 32, 64);
    if (lane < 16) H2[(size_t)wid * 16 + co] = f2bf(p * dv);
}

// ---- agg2: wave/node; 8 slot-groups x 8 ch-lanes x uint, 32-edge blocks ---
__global__ __launch_bounds__(256) void k_agg2(const unsigned short* __restrict__ H2, const int* __restrict__ edges,
                                              const int* __restrict__ start, const int* __restrict__ endv,
                                              const float* __restrict__ dinv,
                                              const float* __restrict__ b2, float* __restrict__ X2, int N) {
    int wid = blockIdx.x * 4 + (threadIdx.x >> 6);
    int lane = threadIdx.x & 63;
    if (wid >= N) return;
    int sg4 = (lane >> 3) * 4;          // slot-group: edges sg4..sg4+3
    int c2 = lane & 7;                  // channels 2*c2, 2*c2+1
    const size_t coff = (size_t)c2 * 2;
    float a0 = 0.f, a1 = 0.f;
    int s = start[wid], e = endv[wid];
    int4 s0;
    if (s < e) s0 = *(const int4*)(edges + s + sg4);
    for (int i = s; i < e; i += 32) {
        int jb = i + sg4;
        int i0 = (jb + 0 < e) ? s0.x : N;
        int i1 = (jb + 1 < e) ? s0.y : N;
        int i2 = (jb + 2 < e) ? s0.z : N;
        int i3 = (jb + 3 < e) ? s0.w : N;
        unsigned int v0 = *(const unsigned int*)(H2 + (size_t)i0 * 16 + coff);
        unsigned int v1 = *(const unsigned int*)(H2 + (size_t)i1 * 16 + coff);
        unsigned int v2 = *(const unsigned int*)(H2 + (size_t)i2 * 16 + coff);
        unsigned int v3 = *(const unsigned int*)(H2 + (size_t)i3 * 16 + coff);
        int ni = i + 32;
        if (ni < e) s0 = *(const int4*)(edges + ni + sg4);
        a0 += __uint_as_float(v0 << 16) + __uint_as_float(v1 << 16)
            + __uint_as_float(v2 << 16) + __uint_as_float(v3 << 16);
        a1 += __uint_as_float(v0 & 0xffff0000u) + __uint_as_float(v1 & 0xffff0000u)
            + __uint_as_float(v2 & 0xffff0000u) + __uint_as_float(v3 & 0xffff0000u);
    }
    a0 += __shfl_xor(a0, 8, 64); a0 += __shfl_xor(a0, 16, 64); a0 += __shfl_xor(a0, 32, 64);
    a1 += __shfl_xor(a1, 8, 64); a1 += __shfl_xor(a1, 16, 64); a1 += __shfl_xor(a1, 32, 64);
    if (lane < 8) {
        float dv = dinv[wid];
        unsigned int sv = *(const unsigned int*)(H2 + (size_t)wid * 16 + coff);  // prescaled self
        a0 += __uint_as_float(sv << 16);
        a1 += __uint_as_float(sv & 0xffff0000u);
        float2 bv = *(const float2*)(b2 + c2 * 2);
        float2 o; o.x = a0 * dv + bv.x; o.y = a1 * dv + bv.y;
        *(float2*)(X2 + (size_t)wid * 16 + coff) = o;
    }
}

// ---- attention head + final linear ----------------------------------------
__global__ __launch_bounds__(256) void k_head(const float* __restrict__ X2, const float* __restrict__ G,
                                              const float* __restrict__ AW1, const float* __restrict__ AB1,
                                              const float* __restrict__ AW2, const float* __restrict__ LW,
                                              const float* __restrict__ LB, float* __restrict__ OUT, int N) {
    __shared__ float s_aw1[256], s_ab1[16], s_aw2[16], s_lw[640], s_lb[40];
    int tid = threadIdx.x;
    s_aw1[tid] = AW1[tid];
    if (tid < 16) { s_ab1[tid] = AB1[tid]; s_aw2[tid] = AW2[tid]; }
    for (int i = tid; i < 640; i += 256) s_lw[i] = LW[i];
    if (tid < 40) s_lb[tid] = LB[tid];
    __syncthreads();
    int node = blockIdx.x * 256 + tid;
    if (node >= N) return;
    float x[16], g[16];
    const float4* xp = (const float4*)(X2 + (size_t)node * 16);
    const float4* gp = (const float4*)(G + (size_t)node * 16);
#pragma unroll
    for (int q = 0; q < 4; ++q) {
        float4 v = xp[q]; x[q*4] = v.x; x[q*4+1] = v.y; x[q*4+2] = v.z; x[q*4+3] = v.w;
        float4 u = gp[q]; g[q*4] = u.x; g[q*4+1] = u.y; g[q*4+2] = u.z; g[q*4+3] = u.w;
    }
    float wx = 0.f, wg = 0.f;
#pragma unroll
    for (int j = 0; j < 16; ++j) {
        float tx = s_ab1[j], tg = s_ab1[j];
#pragma unroll
        for (int c = 0; c < 16; ++c) { tx += x[c] * s_aw1[c*16 + j]; tg += g[c] * s_aw1[c*16 + j]; }
        wx += tanhf(tx) * s_aw2[j];
        wg += tanhf(tg) * s_aw2[j];
    }
    float m = fmaxf(wx, wg);
    float ex = expf(wx - m), eg = expf(wg - m);
    float inv = 1.f / (ex + eg);
    float bx = ex * inv, bg = eg * inv;
    float emb[16];
#pragma unroll
    for (int c = 0; c < 16; ++c) emb[c] = bx * x[c] + bg * g[c];
    float* op = OUT + (size_t)node * 40;
    for (int o = 0; o < 40; ++o) {
        float a = s_lb[o];
#pragma unroll
        for (int c = 0; c < 16; ++c) a += emb[c] * s_lw[c*40 + o];
        op[o] = a;
    }
}

extern "C" void kernel_launch(void* const* d_in, const int* in_sizes, int n_in,
                              void* d_out, int out_size, void* d_ws, size_t ws_size,
                              hipStream_t stream) {
    const float* X   = (const float*)d_in[0];
    const int*   EI  = (const int*)d_in[1];
    const float* G   = (const float*)d_in[2];
    const float* W1  = (const float*)d_in[3];
    const float* B1  = (const float*)d_in[4];
    const float* W2  = (const float*)d_in[5];
    const float* B2  = (const float*)d_in[6];
    const float* AW1 = (const float*)d_in[7];
    const float* AB1 = (const float*)d_in[8];
    const float* AW2 = (const float*)d_in[9];
    const float* LW  = (const float*)d_in[10];
    const float* LB  = (const float*)d_in[11];
    float* OUT = (float*)d_out;

    const int N = in_sizes[0] / N_IN;
    const int E = in_sizes[1] / 2;
    const int NB = (N + 255) / 256;
    const int K  = NB;                 // buckets of 256 destination nodes
    const int NH = K * NBLK;           // hist entries
    const int SB = (NH + 255) / 256;   // scan blocks (== K when NBLK == 256)
    const int WB = (N_IN * HID + 1023) / 1024; // wt blocks (1024 thr)
    const int GB = (N + 127) / 128;            // gemm1 blocks

    char* w = (char*)d_ws;
    size_t off = 0;
    auto take = [&](size_t bytes) -> void* {
        void* p = (void*)(w + off);
        off = (off + bytes + 255) & ~(size_t)255;
        return p;
    };
    int*   hist   = (int*)take((size_t)NH * 4);
    int*   bsum   = (int*)take((size_t)SB * 4);
    int*   bexc   = (int*)take((size_t)(SB + 1) * 4);
    int*   startp = (int*)take((size_t)N * 4);
    int*   endp   = (int*)take((size_t)N * 4);
    float* dinvp  = (float*)take((size_t)N * 4);
    int*   edges2 = (int*)take((size_t)E * 4);
    int*   edges  = (int*)take((size_t)(E + 1024 * (size_t)K + 256) * 4); // aligned-CSR slack + over-read pad
    unsigned short* wt = (unsigned short*)take((size_t)N_IN * HID * 2);
    unsigned short* h1 = (unsigned short*)take((size_t)(N + 1) * 64 * 2); // +zero row N
    unsigned short* h2 = (unsigned short*)take((size_t)(N + 1) * 16 * 2); // +zero row N
    float* x2 = (float*)take((size_t)N * 16 * 4);
    (void)ws_size; (void)n_in; (void)out_size;

    k_histA_wt<<<NBLK + WB, 1024, 0, stream>>>(EI, hist, W1, wt, E, N, K);
    k_scan_a2 <<<SB, 256, 0, stream>>>(hist, bsum, NH);
    k_scan_b  <<<1, 512, 0, stream>>>(bsum, bexc, SB, h1, h2, N);
    k_partB   <<<NBLK, 1024, 0, stream>>>(EI, hist, bexc, edges2, E, N, K);
    k_bucket  <<<K, 256, 0, stream>>>(bexc, edges2, edges, startp, endp, dinvp, N, K);
    k_gemm1   <<<GB, 256, 0, stream>>>(X, wt, dinvp, h1, N);
    k_agg1g2  <<<(N + 3) / 4, 256, 0, stream>>>(h1, edges, startp, endp, dinvp, B1, W2, h2, N);
    k_agg2    <<<(N + 3) / 4, 256, 0, stream>>>(h2, edges, startp, endp, dinvp, B2, x2, N);
    k_head    <<<NB, 256, 0, stream>>>(x2, G, AW1, AB1, AW2, LW, LB, OUT, N);
}

// Round 6
// 525.123 us; speedup vs baseline: 1.0583x; 1.0038x over previous
//
#include <hip/hip_runtime.h>

#define N_IN 512
#define HID 64
#define NBLK 256   // edge-chunk count for hist/partition passes

typedef __attribute__((ext_vector_type(4))) float f32x4;
typedef __attribute__((ext_vector_type(8))) short bf16x8;

__device__ inline float bf2f(unsigned short s) {
    union { unsigned int u; float f; } v; v.u = ((unsigned int)s) << 16; return v.f;
}
__device__ inline unsigned short f2bf(float f) {
    union { float f; unsigned int u; } v; v.f = f;
    unsigned int u = v.u;
    return (unsigned short)((u + 0x7FFFu + ((u >> 16) & 1u)) >> 16);
}

// ---- pass A: per-(bucket, chunk) histogram (LDS atomics) + W1 transpose ----
__global__ __launch_bounds__(1024) void k_histA_wt(const int* __restrict__ EI, int* __restrict__ hist,
                                                   const float* __restrict__ W1, unsigned short* __restrict__ Wt,
                                                   int E, int N, int K) {
    int tid = threadIdx.x;
    if (blockIdx.x >= NBLK) {   // W1 [512][64] fp32 -> Wt [64][512] bf16
        int i = (blockIdx.x - NBLK) * 1024 + tid;
        if (i < N_IN * HID) {
            int k = i >> 6, n = i & 63;
            Wt[n * 512 + k] = f2bf(W1[i]);
        }
        return;
    }
    __shared__ int hs[512];
    __shared__ int sflag;
    if (tid == 0) sflag = (EI[1] == 0 && EI[3] == 0 && EI[5] == 0 && EI[7] == 0) ? 1 : 0;
    if (tid < 512) hs[tid] = 0;
    __syncthreads();
    bool f = sflag != 0;
    int chunk = (E + NBLK - 1) / NBLK;
    int s = blockIdx.x * chunk, e = min(E, s + chunk);
    for (int i = s + tid; i < e; i += 1024) {
        int c = f ? ((const int2*)EI)[E + i].x : EI[E + i];
        if ((unsigned)c < (unsigned)N) atomicAdd(&hs[c >> 8], 1);
    }
    __syncthreads();
    for (int k = tid; k < K; k += 1024) hist[k * NBLK + blockIdx.x] = hs[k];
}

// ---- block-local exclusive scan over hist (in-place) ----
__global__ __launch_bounds__(256) void k_scan_a2(int* __restrict__ data, int* __restrict__ bsum, int n) {
    __shared__ int sd[256];
    int i = blockIdx.x * 256 + threadIdx.x;
    int v = (i < n) ? data[i] : 0;
    sd[threadIdx.x] = v;
    __syncthreads();
    for (int off = 1; off < 256; off <<= 1) {
        int t = 0;
        if (threadIdx.x >= (unsigned)off) t = sd[threadIdx.x - off];
        __syncthreads();
        sd[threadIdx.x] += t;
        __syncthreads();
    }
    if (i < n) data[i] = sd[threadIdx.x] - v;
    if (threadIdx.x == 255) bsum[blockIdx.x] = sd[255];
}

// also zeroes the pad rows (row N) of h1/h2 used by predicated gathers
__global__ __launch_bounds__(512) void k_scan_b(const int* __restrict__ bsum, int* __restrict__ bexc, int nb,
                                                unsigned short* __restrict__ h1, unsigned short* __restrict__ h2,
                                                int N) {
    __shared__ int sd[512];
    int t = threadIdx.x;
    if (t < 32) ((unsigned int*)(h1 + (size_t)N * 64))[t] = 0;          // 128B zero row
    if (t >= 32 && t < 40) ((unsigned int*)(h2 + (size_t)N * 16))[t - 32] = 0;  // 32B zero row
    int v = (t < nb) ? bsum[t] : 0;
    sd[t] = v;
    __syncthreads();
    for (int off = 1; off < 512; off <<= 1) {
        int u = 0;
        if (t >= off) u = sd[t - off];
        __syncthreads();
        sd[t] += u;
        __syncthreads();
    }
    if (t < nb) bexc[t] = sd[t] - v;
    if (t == 511) bexc[nb] = sd[511];
}

// ---- pass B: simple scatter ------------------------------------------------
__global__ __launch_bounds__(1024) void k_partB(const int* __restrict__ EI, const int* __restrict__ hist,
                                                const int* __restrict__ bexc, int* __restrict__ edges2,
                                                int E, int N, int K) {
    __shared__ int cur[512];
    __shared__ int sflag;
    int tid = threadIdx.x, b = blockIdx.x;
    if (tid == 0) sflag = (EI[1] == 0 && EI[3] == 0 && EI[5] == 0 && EI[7] == 0) ? 1 : 0;
    if (tid < 512) cur[tid] = (tid < K) ? (bexc[tid] + hist[tid * NBLK + b]) : 0;
    __syncthreads();
    bool f = sflag != 0;
    int chunk = (E + NBLK - 1) / NBLK;
    int s = b * chunk, e = min(E, s + chunk);
    for (int i = s + tid; i < e; i += 1024) {
        int r, c;
        if (f) { const int2* E2 = (const int2*)EI; r = E2[i].x; c = E2[E + i].x; }
        else   { r = EI[i]; c = EI[E + i]; }
        if ((unsigned)r >= (unsigned)N || (unsigned)c >= (unsigned)N) continue;
        int pos = atomicAdd(&cur[c >> 8], 1);
        edges2[pos] = r | ((c & 255) << 20);   // r < 2^20, c_local in bits 20..27
    }
}

// ---- per-bucket: fine CSR (4-aligned starts, se/dinv + edge scatter) ------
// Fine region for bucket b: align4(bexc[b]) + 1024*b; start % 4 == 0.
__global__ __launch_bounds__(256) void k_bucket(const int* __restrict__ bexc, const int* __restrict__ edges2,
                                                int* __restrict__ edges, int2* __restrict__ sep,
                                                float* __restrict__ dinv, int N, int K) {
    __shared__ int hist[256], sd[256], cur[256];
    int b = blockIdx.x, tid = threadIdx.x;
    int cbase = bexc[b];
    int cend  = bexc[b + 1];
    int base  = ((cbase + 3) & ~3) + 1024 * b;   // 4-aligned fine base
    hist[tid] = 0;
    __syncthreads();
    for (int i = cbase + tid; i < cend; i += 256)
        atomicAdd(&hist[(edges2[i] >> 20) & 255], 1);
    __syncthreads();
    int v = hist[tid];
    int v4 = (v + 3) & ~3;
    sd[tid] = v4;
    __syncthreads();
    for (int off = 1; off < 256; off <<= 1) {
        int t = 0;
        if (tid >= off) t = sd[tid - off];
        __syncthreads();
        sd[tid] += t;
        __syncthreads();
    }
    int excl = sd[tid] - v4;
    cur[tid] = excl;
    int node = b * 256 + tid;
    if (node < N) {
        int st = base + excl;
        sep[node] = make_int2(st, st + v);
        dinv[node] = rsqrtf((float)(v + 1));
    }
    __syncthreads();
    for (int i = cbase + tid; i < cend; i += 256) {
        int pv = edges2[i];
        int pos = atomicAdd(&cur[(pv >> 20) & 255], 1);
        edges[base + pos] = pv & 0xFFFFF;
    }
}

// ---- GEMM1 (MFMA, no LDS): H[m] = dinv[m] * (X[m]·W1) in bf16 -------------
__global__ __launch_bounds__(256) void k_gemm1(const float* __restrict__ X, const unsigned short* __restrict__ Wt,
                                               const float* __restrict__ dinv, unsigned short* __restrict__ H,
                                               int N) {
    int tid = threadIdx.x;
    int w = tid >> 6, lane = tid & 63;
    int m_l = lane & 15, q = lane >> 4;
    int m0 = blockIdx.x * 128 + w * 32;
    int rA0 = m0 + m_l, rA1 = m0 + 16 + m_l;
    int rc0 = rA0 < N ? rA0 : N - 1;
    int rc1 = rA1 < N ? rA1 : N - 1;
    const float* baseA0 = X + (size_t)rc0 * 512 + q * 8;
    const float* baseA1 = X + (size_t)rc1 * 512 + q * 8;
    const unsigned short* baseB = Wt + (size_t)m_l * 512 + q * 8;

    f32x4 acc[2][4] = {};
#pragma unroll 4
    for (int c = 0; c < 16; ++c) {
        int ko = c * 32;
        float4 x0a = *(const float4*)(baseA0 + ko);
        float4 x0b = *(const float4*)(baseA0 + ko + 4);
        float4 x1a = *(const float4*)(baseA1 + ko);
        float4 x1b = *(const float4*)(baseA1 + ko + 4);
        bf16x8 a0, a1;
        a0[0] = (short)f2bf(x0a.x); a0[1] = (short)f2bf(x0a.y); a0[2] = (short)f2bf(x0a.z); a0[3] = (short)f2bf(x0a.w);
        a0[4] = (short)f2bf(x0b.x); a0[5] = (short)f2bf(x0b.y); a0[6] = (short)f2bf(x0b.z); a0[7] = (short)f2bf(x0b.w);
        a1[0] = (short)f2bf(x1a.x); a1[1] = (short)f2bf(x1a.y); a1[2] = (short)f2bf(x1a.z); a1[3] = (short)f2bf(x1a.w);
        a1[4] = (short)f2bf(x1b.x); a1[5] = (short)f2bf(x1b.y); a1[6] = (short)f2bf(x1b.z); a1[7] = (short)f2bf(x1b.w);
#pragma unroll
        for (int t = 0; t < 4; ++t) {
            bf16x8 bb = *(const bf16x8*)(baseB + (size_t)t * 16 * 512 + ko);
            acc[0][t] = __builtin_amdgcn_mfma_f32_16x16x32_bf16(a0, bb, acc[0][t], 0, 0, 0);
            acc[1][t] = __builtin_amdgcn_mfma_f32_16x16x32_bf16(a1, bb, acc[1][t], 0, 0, 0);
        }
    }
#pragma unroll
    for (int h = 0; h < 2; ++h) {
#pragma unroll
        for (int rg = 0; rg < 4; ++rg) {
            int row = m0 + h * 16 + q * 4 + rg;
            if (row < N) {
                float dv = dinv[row];
#pragma unroll
                for (int t = 0; t < 4; ++t)
                    H[(size_t)row * 64 + t * 16 + m_l] = f2bf(acc[h][t][rg] * dv);
            }
        }
    }
}

#define ACC8(v) do { \
    a[0] += __uint_as_float((v).x << 16); \
    a[1] += __uint_as_float((v).x & 0xffff0000u); \
    a[2] += __uint_as_float((v).y << 16); \
    a[3] += __uint_as_float((v).y & 0xffff0000u); \
    a[4] += __uint_as_float((v).z << 16); \
    a[5] += __uint_as_float((v).z & 0xffff0000u); \
    a[6] += __uint_as_float((v).w << 16); \
    a[7] += __uint_as_float((v).w & 0xffff0000u); } while (0)

// ---- fused agg1 + gemm2: wave/node; 8 slot-groups x 8 ch-lanes x uint4.
// 32-edge blocks; predicated to zero-row N; __launch_bounds__(256,8) to force
// <=64 VGPR -> 8 waves/SIMD for latency hiding.
__global__ __launch_bounds__(256, 8) void k_agg1g2(const unsigned short* __restrict__ H, const int* __restrict__ edges,
                                                   const int2* __restrict__ sep, const float* __restrict__ dinv,
                                                   const float* __restrict__ b1, const float* __restrict__ W2,
                                                   unsigned short* __restrict__ H2, int N) {
    __shared__ float w2s[64 * 17];   // [k][c] stride 17
    int tid = threadIdx.x;
    for (int i = tid; i < 1024; i += 256) { int k = i >> 4, c = i & 15; w2s[k * 17 + c] = W2[i]; }
    __syncthreads();
    int wid = blockIdx.x * 4 + (tid >> 6);
    int lane = tid & 63;
    if (wid >= N) return;
    int sg4 = (lane >> 3) * 4;          // slot-group: edges sg4..sg4+3 of each block
    int c8 = lane & 7;                  // channels 8*c8 .. 8*c8+7 (16B of the row)
    const size_t coff = (size_t)c8 * 8;
    float a[8] = {0.f, 0.f, 0.f, 0.f, 0.f, 0.f, 0.f, 0.f};
    int2 se = sep[wid];
    int s = se.x, e = se.y;
    int4 s0;
    if (s < e) s0 = *(const int4*)(edges + s + sg4);   // start 4-aligned
    for (int i = s; i < e; i += 32) {
        int jb = i + sg4;
        int i0 = (jb + 0 < e) ? s0.x : N;
        int i1 = (jb + 1 < e) ? s0.y : N;
        int i2 = (jb + 2 < e) ? s0.z : N;
        int i3 = (jb + 3 < e) ? s0.w : N;
        uint4 v0 = *(const uint4*)(H + (size_t)i0 * 64 + coff);
        uint4 v1 = *(const uint4*)(H + (size_t)i1 * 64 + coff);
        uint4 v2 = *(const uint4*)(H + (size_t)i2 * 64 + coff);
        uint4 v3 = *(const uint4*)(H + (size_t)i3 * 64 + coff);
        int ni = i + 32;
        if (ni < e) s0 = *(const int4*)(edges + ni + sg4);   // prefetch
        ACC8(v0); ACC8(v1); ACC8(v2); ACC8(v3);
    }
    // butterfly over the 8 slot-groups
#pragma unroll
    for (int c = 0; c < 8; ++c) {
        a[c] += __shfl_xor(a[c], 8, 64);
        a[c] += __shfl_xor(a[c], 16, 64);
        a[c] += __shfl_xor(a[c], 32, 64);
    }
    // self term + bias + relu
    float dv = dinv[wid];
    uint4 sv = *(const uint4*)(H + (size_t)wid * 64 + coff);   // prescaled self
    ACC8(sv);
    float4 bva = *(const float4*)(b1 + c8 * 8);
    float4 bvb = *(const float4*)(b1 + c8 * 8 + 4);
    float r[8];
    r[0] = fmaxf(a[0] * dv + bva.x, 0.f);
    r[1] = fmaxf(a[1] * dv + bva.y, 0.f);
    r[2] = fmaxf(a[2] * dv + bva.z, 0.f);
    r[3] = fmaxf(a[3] * dv + bva.w, 0.f);
    r[4] = fmaxf(a[4] * dv + bvb.x, 0.f);
    r[5] = fmaxf(a[5] * dv + bvb.y, 0.f);
    r[6] = fmaxf(a[6] * dv + bvb.z, 0.f);
    r[7] = fmaxf(a[7] * dv + bvb.w, 0.f);
    // fused gemm2: x1[k] lives in lane with lane&7==k>>3, register k&7.
    // lane (qt=lane>>4, co=lane&15) accumulates k = qt*16 .. qt*16+15.
    int qt = lane >> 4, co = lane & 15;
    float p = 0.f;
#pragma unroll
    for (int j = 0; j < 16; ++j) {
        float xk = __shfl(r[j & 7], qt * 2 + (j >> 3), 64);
        p += xk * w2s[(qt * 16 + j) * 17 + co];
    }
    p += __shfl_xor(p, 16, 64);
    p += __shfl_xor(p, 32, 64);
    if (lane < 16) H2[(size_t)wid * 16 + co] = f2bf(p * dv);
}

// ---- agg2: wave/node; 8 slot-groups x 8 ch-lanes x uint, 32-edge blocks ---
__global__ __launch_bounds__(256, 8) void k_agg2(const unsigned short* __restrict__ H2, const int* __restrict__ edges,
                                                 const int2* __restrict__ sep, const float* __restrict__ dinv,
                                                 const float* __restrict__ b2, float* __restrict__ X2, int N) {
    int wid = blockIdx.x * 4 + (threadIdx.x >> 6);
    int lane = threadIdx.x & 63;
    if (wid >= N) return;
    int sg4 = (lane >> 3) * 4;          // slot-group: edges sg4..sg4+3
    int c2 = lane & 7;                  // channels 2*c2, 2*c2+1
    const size_t coff = (size_t)c2 * 2;
    float a0 = 0.f, a1 = 0.f;
    int2 se = sep[wid];
    int s = se.x, e = se.y;
    int4 s0;
    if (s < e) s0 = *(const int4*)(edges + s + sg4);
    for (int i = s; i < e; i += 32) {
        int jb = i + sg4;
        int i0 = (jb + 0 < e) ? s0.x : N;
        int i1 = (jb + 1 < e) ? s0.y : N;
        int i2 = (jb + 2 < e) ? s0.z : N;
        int i3 = (jb + 3 < e) ? s0.w : N;
        unsigned int v0 = *(const unsigned int*)(H2 + (size_t)i0 * 16 + coff);
        unsigned int v1 = *(const unsigned int*)(H2 + (size_t)i1 * 16 + coff);
        unsigned int v2 = *(const unsigned int*)(H2 + (size_t)i2 * 16 + coff);
        unsigned int v3 = *(const unsigned int*)(H2 + (size_t)i3 * 16 + coff);
        int ni = i + 32;
        if (ni < e) s0 = *(const int4*)(edges + ni + sg4);
        a0 += __uint_as_float(v0 << 16) + __uint_as_float(v1 << 16)
            + __uint_as_float(v2 << 16) + __uint_as_float(v3 << 16);
        a1 += __uint_as_float(v0 & 0xffff0000u) + __uint_as_float(v1 & 0xffff0000u)
            + __uint_as_float(v2 & 0xffff0000u) + __uint_as_float(v3 & 0xffff0000u);
    }
    a0 += __shfl_xor(a0, 8, 64); a0 += __shfl_xor(a0, 16, 64); a0 += __shfl_xor(a0, 32, 64);
    a1 += __shfl_xor(a1, 8, 64); a1 += __shfl_xor(a1, 16, 64); a1 += __shfl_xor(a1, 32, 64);
    if (lane < 8) {
        float dv = dinv[wid];
        unsigned int sv = *(const unsigned int*)(H2 + (size_t)wid * 16 + coff);  // prescaled self
        a0 += __uint_as_float(sv << 16);
        a1 += __uint_as_float(sv & 0xffff0000u);
        float2 bv = *(const float2*)(b2 + c2 * 2);
        float2 o; o.x = a0 * dv + bv.x; o.y = a1 * dv + bv.y;
        *(float2*)(X2 + (size_t)wid * 16 + coff) = o;
    }
}

// ---- attention head + final linear ----------------------------------------
__global__ __launch_bounds__(256) void k_head(const float* __restrict__ X2, const float* __restrict__ G,
                                              const float* __restrict__ AW1, const float* __restrict__ AB1,
                                              const float* __restrict__ AW2, const float* __restrict__ LW,
                                              const float* __restrict__ LB, float* __restrict__ OUT, int N) {
    __shared__ float s_aw1[256], s_ab1[16], s_aw2[16], s_lw[640], s_lb[40];
    int tid = threadIdx.x;
    s_aw1[tid] = AW1[tid];
    if (tid < 16) { s_ab1[tid] = AB1[tid]; s_aw2[tid] = AW2[tid]; }
    for (int i = tid; i < 640; i += 256) s_lw[i] = LW[i];
    if (tid < 40) s_lb[tid] = LB[tid];
    __syncthreads();
    int node = blockIdx.x * 256 + tid;
    if (node >= N) return;
    float x[16], g[16];
    const float4* xp = (const float4*)(X2 + (size_t)node * 16);
    const float4* gp = (const float4*)(G + (size_t)node * 16);
#pragma unroll
    for (int q = 0; q < 4; ++q) {
        float4 v = xp[q]; x[q*4] = v.x; x[q*4+1] = v.y; x[q*4+2] = v.z; x[q*4+3] = v.w;
        float4 u = gp[q]; g[q*4] = u.x; g[q*4+1] = u.y; g[q*4+2] = u.z; g[q*4+3] = u.w;
    }
    float wx = 0.f, wg = 0.f;
#pragma unroll
    for (int j = 0; j < 16; ++j) {
        float tx = s_ab1[j], tg = s_ab1[j];
#pragma unroll
        for (int c = 0; c < 16; ++c) { tx += x[c] * s_aw1[c*16 + j]; tg += g[c] * s_aw1[c*16 + j]; }
        wx += tanhf(tx) * s_aw2[j];
        wg += tanhf(tg) * s_aw2[j];
    }
    float m = fmaxf(wx, wg);
    float ex = expf(wx - m), eg = expf(wg - m);
    float inv = 1.f / (ex + eg);
    float bx = ex * inv, bg = eg * inv;
    float emb[16];
#pragma unroll
    for (int c = 0; c < 16; ++c) emb[c] = bx * x[c] + bg * g[c];
    float* op = OUT + (size_t)node * 40;
    for (int o = 0; o < 40; ++o) {
        float a = s_lb[o];
#pragma unroll
        for (int c = 0; c < 16; ++c) a += emb[c] * s_lw[c*40 + o];
        op[o] = a;
    }
}

extern "C" void kernel_launch(void* const* d_in, const int* in_sizes, int n_in,
                              void* d_out, int out_size, void* d_ws, size_t ws_size,
                              hipStream_t stream) {
    const float* X   = (const float*)d_in[0];
    const int*   EI  = (const int*)d_in[1];
    const float* G   = (const float*)d_in[2];
    const float* W1  = (const float*)d_in[3];
    const float* B1  = (const float*)d_in[4];
    const float* W2  = (const float*)d_in[5];
    const float* B2  = (const float*)d_in[6];
    const float* AW1 = (const float*)d_in[7];
    const float* AB1 = (const float*)d_in[8];
    const float* AW2 = (const float*)d_in[9];
    const float* LW  = (const float*)d_in[10];
    const float* LB  = (const float*)d_in[11];
    float* OUT = (float*)d_out;

    const int N = in_sizes[0] / N_IN;
    const int E = in_sizes[1] / 2;
    const int NB = (N + 255) / 256;
    const int K  = NB;                 // buckets of 256 destination nodes
    const int NH = K * NBLK;           // hist entries
    const int SB = (NH + 255) / 256;   // scan blocks (== K when NBLK == 256)
    const int WB = (N_IN * HID + 1023) / 1024; // wt blocks (1024 thr)
    const int GB = (N + 127) / 128;            // gemm1 blocks

    char* w = (char*)d_ws;
    size_t off = 0;
    auto take = [&](size_t bytes) -> void* {
        void* p = (void*)(w + off);
        off = (off + bytes + 255) & ~(size_t)255;
        return p;
    };
    int*   hist   = (int*)take((size_t)NH * 4);
    int*   bsum   = (int*)take((size_t)SB * 4);
    int*   bexc   = (int*)take((size_t)(SB + 1) * 4);
    int2*  sep    = (int2*)take((size_t)N * 8);
    float* dinvp  = (float*)take((size_t)N * 4);
    int*   edges2 = (int*)take((size_t)E * 4);
    int*   edges  = (int*)take((size_t)(E + 1024 * (size_t)K + 256) * 4); // aligned-CSR slack + over-read pad
    unsigned short* wt = (unsigned short*)take((size_t)N_IN * HID * 2);
    unsigned short* h1 = (unsigned short*)take((size_t)(N + 1) * 64 * 2); // +zero row N
    unsigned short* h2 = (unsigned short*)take((size_t)(N + 1) * 16 * 2); // +zero row N
    float* x2 = (float*)take((size_t)N * 16 * 4);
    (void)ws_size; (void)n_in; (void)out_size;

    k_histA_wt<<<NBLK + WB, 1024, 0, stream>>>(EI, hist, W1, wt, E, N, K);
    k_scan_a2 <<<SB, 256, 0, stream>>>(hist, bsum, NH);
    k_scan_b  <<<1, 512, 0, stream>>>(bsum, bexc, SB, h1, h2, N);
    k_partB   <<<NBLK, 1024, 0, stream>>>(EI, hist, bexc, edges2, E, N, K);
    k_bucket  <<<K, 256, 0, stream>>>(bexc, edges2, edges, sep, dinvp, N, K);
    k_gemm1   <<<GB, 256, 0, stream>>>(X, wt, dinvp, h1, N);
    k_agg1g2  <<<(N + 3) / 4, 256, 0, stream>>>(h1, edges, sep, dinvp, B1, W2, h2, N);
    k_agg2    <<<(N + 3) / 4, 256, 0, stream>>>(h2, edges, sep, dinvp, B2, x2, N);
    k_head    <<<NB, 256, 0, stream>>>(x2, G, AW1, AB1, AW2, LW, LB, OUT, N);
}